// Round 1
// baseline (901.199 us; speedup 1.0000x reference)
//
#include <hip/hip_runtime.h>
#include <math.h>

#define NEG_SLOPE 0.2f
#define BN_EPS 1e-5f

static __device__ __forceinline__ float wave_red_sum(float v) {
    for (int off = 32; off; off >>= 1) v += __shfl_xor(v, off);
    return v;
}

// ---------------- CSR build ----------------
__global__ void k_init_counts(int* counts, int n) {
    int i = blockIdx.x * blockDim.x + threadIdx.x;
    if (i < n) counts[i] = 1;  // self-loop reserved
}

__global__ void k_hist(const int* __restrict__ dst, int E, int* __restrict__ counts) {
    int stride = gridDim.x * blockDim.x;
    for (int i = blockIdx.x * blockDim.x + threadIdx.x; i < E; i += stride)
        atomicAdd(&counts[dst[i]], 1);
}

// exclusive scan, 1024 elems/block (256 thr x 4)
__global__ void k_scan_block(const int* __restrict__ in, int* __restrict__ out,
                             int* __restrict__ bsums, int n) {
    __shared__ int lds[256];
    int tid = threadIdx.x;
    int base = blockIdx.x * 1024 + tid * 4;
    int v0 = 0, v1 = 0, v2 = 0, v3 = 0;
    if (base + 0 < n) v0 = in[base + 0];
    if (base + 1 < n) v1 = in[base + 1];
    if (base + 2 < n) v2 = in[base + 2];
    if (base + 3 < n) v3 = in[base + 3];
    int s = v0 + v1 + v2 + v3;
    lds[tid] = s;
    __syncthreads();
    for (int off = 1; off < 256; off <<= 1) {
        int t = (tid >= off) ? lds[tid - off] : 0;
        __syncthreads();
        lds[tid] += t;
        __syncthreads();
    }
    int excl = lds[tid] - s;
    if (base + 0 < n) out[base + 0] = excl; excl += v0;
    if (base + 1 < n) out[base + 1] = excl; excl += v1;
    if (base + 2 < n) out[base + 2] = excl; excl += v2;
    if (base + 3 < n) out[base + 3] = excl;
    if (tid == 255) bsums[blockIdx.x] = lds[255];
}

__global__ void k_scan_bsums(int* bsums, int nb, int* total) {
    if (threadIdx.x == 0 && blockIdx.x == 0) {
        int run = 0;
        for (int i = 0; i < nb; i++) { int t = bsums[i]; bsums[i] = run; run += t; }
        *total = run;
    }
}

__global__ void k_scan_add(int* __restrict__ out, const int* __restrict__ bsums, int n) {
    int base = blockIdx.x * 1024 + threadIdx.x * 4;
    int add = bsums[blockIdx.x];
    #pragma unroll
    for (int i = 0; i < 4; i++)
        if (base + i < n) out[base + i] += add;
}

__global__ void k_selfloop(const int* __restrict__ row_ptr, int* __restrict__ csr_src,
                           int* __restrict__ cursor, int n) {
    int i = blockIdx.x * blockDim.x + threadIdx.x;
    if (i < n) { int rp = row_ptr[i]; csr_src[rp] = i; cursor[i] = rp + 1; }
}

__global__ void k_scatter(const int* __restrict__ src, const int* __restrict__ dst, int E,
                          int* __restrict__ cursor, int* __restrict__ csr_src) {
    int stride = gridDim.x * blockDim.x;
    for (int i = blockIdx.x * blockDim.x + threadIdx.x; i < E; i += stride) {
        int d = dst[i];
        int pos = atomicAdd(&cursor[d], 1);
        csr_src[pos] = src[i];
    }
}

// ---------------- per-node matmul + scores (optionally fused input BN+ReLU) ----------------
template <int FIN, int USE_BN>
__global__ void __launch_bounds__(256) k_gemm(
    const float* __restrict__ X, const float* __restrict__ W,
    const float* __restrict__ a_src, const float* __restrict__ a_dst,
    const float* __restrict__ bn_sc, const float* __restrict__ bn_sh,
    float* __restrict__ H, float* __restrict__ S, float* __restrict__ Dv, int n) {
    __shared__ float Wl[FIN * 64];
    for (int i = threadIdx.x; i < FIN * 64; i += 256) Wl[i] = W[i];
    __syncthreads();
    int wave = threadIdx.x >> 6, lane = threadIdx.x & 63;
    int node = blockIdx.x * 4 + wave;
    if (node >= n) return;
    const float* xr = X + (size_t)node * FIN;
    float acc = 0.f;
    #pragma unroll 4
    for (int k = 0; k < FIN; k++) {
        float xv = xr[k];
        if (USE_BN) xv = fmaxf(fmaf(xv, bn_sc[k], bn_sh[k]), 0.f);
        acc = fmaf(xv, Wl[k * 64 + lane], acc);
    }
    H[(size_t)node * 64 + lane] = acc;
    float ps = wave_red_sum(acc * a_src[lane]);
    float pd = wave_red_sum(acc * a_dst[lane]);
    if (lane == 0) { S[node] = ps; Dv[node] = pd; }
}

// ---------------- node-parallel GAT aggregate, online softmax ----------------
__global__ void __launch_bounds__(256) k_aggregate(
    const float* __restrict__ H, const float* __restrict__ S, const float* __restrict__ Dv,
    const int* __restrict__ row_ptr, const int* __restrict__ csr_src,
    const float* __restrict__ bias, float* __restrict__ out, int n) {
    int wave = threadIdx.x >> 6, lane = threadIdx.x & 63;
    int node = blockIdx.x * 4 + wave;
    if (node >= n) return;
    int start = row_ptr[node], end = row_ptr[node + 1];
    float dn = Dv[node];
    float m = -1e30f, z = 0.f, acc = 0.f;
    for (int base = start; base < end; base += 64) {
        int cnt = min(64, end - base);
        int sj = 0;
        float e = -1e30f;
        if (lane < cnt) {
            sj = csr_src[base + lane];
            float t = S[sj] + dn;
            e = (t > 0.f) ? t : NEG_SLOPE * t;
        }
        float cm = e;
        for (int off = 32; off; off >>= 1) cm = fmaxf(cm, __shfl_xor(cm, off));
        float newm = fmaxf(m, cm);
        float rescale = __expf(m - newm);  // m=-1e30 first pass -> 0
        float w = (lane < cnt) ? __expf(e - newm) : 0.f;
        float ws = w;
        for (int off = 32; off; off >>= 1) ws += __shfl_xor(ws, off);
        z = z * rescale + ws;
        acc *= rescale;
        for (int jj = 0; jj < cnt; jj++) {
            float wj = __shfl(w, jj);
            int sjj = __shfl(sj, jj);
            acc = fmaf(wj, H[(size_t)sjj * 64 + lane], acc);
        }
        m = newm;
    }
    out[(size_t)node * 64 + lane] = acc / z + bias[lane];
}

// ---------------- batchnorm stats ----------------
__global__ void k_zero_stats(float* stats) {
    if (threadIdx.x < 128) stats[threadIdx.x] = 0.f;
}

__global__ void __launch_bounds__(256) k_colstats(const float* __restrict__ T, int n,
                                                  float* __restrict__ sums,
                                                  float* __restrict__ sumsq) {
    __shared__ float ls[256], lq[256];
    int f = threadIdx.x & 63;
    int rowgrp = threadIdx.x >> 6;
    float s = 0.f, q = 0.f;
    for (int r = blockIdx.x * 4 + rowgrp; r < n; r += gridDim.x * 4) {
        float v = T[(size_t)r * 64 + f];
        s += v;
        q += v * v;
    }
    ls[threadIdx.x] = s; lq[threadIdx.x] = q;
    __syncthreads();
    if (threadIdx.x < 128) {
        ls[threadIdx.x] += ls[threadIdx.x + 128];
        lq[threadIdx.x] += lq[threadIdx.x + 128];
    }
    __syncthreads();
    if (threadIdx.x < 64) {
        atomicAdd(&sums[f], ls[threadIdx.x] + ls[threadIdx.x + 64]);
        atomicAdd(&sumsq[f], lq[threadIdx.x] + lq[threadIdx.x + 64]);
    }
}

__global__ void k_bn_finalize(const float* __restrict__ sums, const float* __restrict__ sumsq,
                              const float* __restrict__ g, const float* __restrict__ be,
                              int n, float* __restrict__ sc, float* __restrict__ sh) {
    int f = threadIdx.x;
    if (f < 64) {
        float inv_n = 1.f / (float)n;
        float mu = sums[f] * inv_n;
        float var = sumsq[f] * inv_n - mu * mu;
        float rstd = rsqrtf(var + BN_EPS);
        float scale = rstd * g[f];
        sc[f] = scale;
        sh[f] = be[f] - mu * scale;
    }
}

extern "C" void kernel_launch(void* const* d_in, const int* in_sizes, int n_in,
                              void* d_out, int out_size, void* d_ws, size_t ws_size,
                              hipStream_t stream) {
    const float* x        = (const float*)d_in[0];
    const int*   ei       = (const int*)d_in[1];
    const float* W_in     = (const float*)d_in[2];
    const float* a_src_in = (const float*)d_in[3];
    const float* a_dst_in = (const float*)d_in[4];
    const float* b_in     = (const float*)d_in[5];
    const float* W_mid    = (const float*)d_in[6];
    const float* a_src_mid= (const float*)d_in[7];
    const float* a_dst_mid= (const float*)d_in[8];
    const float* b_mid    = (const float*)d_in[9];
    const float* gamma    = (const float*)d_in[10];
    const float* beta     = (const float*)d_in[11];
    const float* W_out    = (const float*)d_in[12];
    const float* a_src_out= (const float*)d_in[13];
    const float* a_dst_out= (const float*)d_in[14];
    const float* b_out    = (const float*)d_in[15];

    int n = in_sizes[0] / 128;   // 50000
    int E = in_sizes[1] / 2;     // 1250000
    const int* srcE = ei;
    const int* dstE = ei + E;

    auto alignup = [](size_t v) { return (v + 255) & ~(size_t)255; };
    char* p = (char*)d_ws;
    int* counts  = (int*)p; p += alignup((size_t)n * 4);
    int* row_ptr = (int*)p; p += alignup((size_t)(n + 1) * 4);
    int nb = (n + 1023) / 1024;
    int* bsums   = (int*)p; p += alignup((size_t)nb * 4);
    int* cursor  = (int*)p; p += alignup((size_t)n * 4);
    int* csr     = (int*)p; p += alignup((size_t)(E + n) * 4);
    float* H     = (float*)p; p += alignup((size_t)n * 64 * 4);
    float* S     = (float*)p; p += alignup((size_t)n * 4);
    float* Dv    = (float*)p; p += alignup((size_t)n * 4);
    float* stats = (float*)p; p += alignup(128 * 4);
    float* bnsc  = (float*)p; p += alignup(64 * 4);
    float* bnsh  = (float*)p; p += alignup(64 * 4);
    float* T     = (float*)d_out;  // layer ping buffer; final aggregate rewrites it

    // ---- CSR build (edges identical across all 5 layers) ----
    k_init_counts<<<(n + 255) / 256, 256, 0, stream>>>(counts, n);
    k_hist<<<2048, 256, 0, stream>>>(dstE, E, counts);
    k_scan_block<<<nb, 256, 0, stream>>>(counts, row_ptr, bsums, n);
    k_scan_bsums<<<1, 64, 0, stream>>>(bsums, nb, row_ptr + n);
    k_scan_add<<<nb, 256, 0, stream>>>(row_ptr, bsums, n);
    k_selfloop<<<(n + 255) / 256, 256, 0, stream>>>(row_ptr, csr, cursor, n);
    k_scatter<<<2048, 256, 0, stream>>>(srcE, dstE, E, cursor, csr);

    int gb = (n + 3) / 4;

    // ---- input GAT layer ----
    k_gemm<128, 0><<<gb, 256, 0, stream>>>(x, W_in, a_src_in, a_dst_in, nullptr, nullptr,
                                           H, S, Dv, n);
    k_aggregate<<<gb, 256, 0, stream>>>(H, S, Dv, row_ptr, csr, b_in, T, n);

    // ---- mid layers: gat -> BN stats; BN+ReLU fused into next gemm's input ----
    for (int l = 0; l < 3; l++) {
        if (l == 0)
            k_gemm<64, 0><<<gb, 256, 0, stream>>>(T, W_mid + l * 4096, a_src_mid + l * 64,
                                                  a_dst_mid + l * 64, nullptr, nullptr,
                                                  H, S, Dv, n);
        else
            k_gemm<64, 1><<<gb, 256, 0, stream>>>(T, W_mid + l * 4096, a_src_mid + l * 64,
                                                  a_dst_mid + l * 64, bnsc, bnsh,
                                                  H, S, Dv, n);
        k_aggregate<<<gb, 256, 0, stream>>>(H, S, Dv, row_ptr, csr, b_mid + l * 64, T, n);
        k_zero_stats<<<1, 128, 0, stream>>>(stats);
        k_colstats<<<512, 256, 0, stream>>>(T, n, stats, stats + 64);
        k_bn_finalize<<<1, 64, 0, stream>>>(stats, stats + 64, gamma + l * 64, beta + l * 64,
                                            n, bnsc, bnsh);
    }

    // ---- output GAT layer (consumes BN+ReLU of last mid layer) ----
    k_gemm<64, 1><<<gb, 256, 0, stream>>>(T, W_out, a_src_out, a_dst_out, bnsc, bnsh,
                                          H, S, Dv, n);
    k_aggregate<<<gb, 256, 0, stream>>>(H, S, Dv, row_ptr, csr, b_out, (float*)d_out, n);
}

// Round 2
// 801.747 us; speedup vs baseline: 1.1240x; 1.1240x over previous
//
#include <hip/hip_runtime.h>
#include <math.h>

#define NEG_SLOPE 0.2f
#define BN_EPS 1e-5f

static __device__ __forceinline__ float wave_red_sum(float v) {
    for (int off = 32; off; off >>= 1) v += __shfl_xor(v, off);
    return v;
}

// ---------------- CSR build ----------------
__global__ void k_init_counts(int* counts, int n) {
    int i = blockIdx.x * blockDim.x + threadIdx.x;
    if (i < n) counts[i] = 1;  // self-loop reserved
}

__global__ void k_hist(const int* __restrict__ dst, int E, int* __restrict__ counts) {
    int stride = gridDim.x * blockDim.x;
    for (int i = blockIdx.x * blockDim.x + threadIdx.x; i < E; i += stride)
        atomicAdd(&counts[dst[i]], 1);
}

// exclusive scan, 1024 elems/block (256 thr x 4)
__global__ void k_scan_block(const int* __restrict__ in, int* __restrict__ out,
                             int* __restrict__ bsums, int n) {
    __shared__ int lds[256];
    int tid = threadIdx.x;
    int base = blockIdx.x * 1024 + tid * 4;
    int v0 = 0, v1 = 0, v2 = 0, v3 = 0;
    if (base + 0 < n) v0 = in[base + 0];
    if (base + 1 < n) v1 = in[base + 1];
    if (base + 2 < n) v2 = in[base + 2];
    if (base + 3 < n) v3 = in[base + 3];
    int s = v0 + v1 + v2 + v3;
    lds[tid] = s;
    __syncthreads();
    for (int off = 1; off < 256; off <<= 1) {
        int t = (tid >= off) ? lds[tid - off] : 0;
        __syncthreads();
        lds[tid] += t;
        __syncthreads();
    }
    int excl = lds[tid] - s;
    if (base + 0 < n) out[base + 0] = excl; excl += v0;
    if (base + 1 < n) out[base + 1] = excl; excl += v1;
    if (base + 2 < n) out[base + 2] = excl; excl += v2;
    if (base + 3 < n) out[base + 3] = excl;
    if (tid == 255) bsums[blockIdx.x] = lds[255];
}

__global__ void k_scan_bsums(int* bsums, int nb, int* total) {
    if (threadIdx.x == 0 && blockIdx.x == 0) {
        int run = 0;
        for (int i = 0; i < nb; i++) { int t = bsums[i]; bsums[i] = run; run += t; }
        *total = run;
    }
}

__global__ void k_scan_add(int* __restrict__ out, const int* __restrict__ bsums, int n) {
    int base = blockIdx.x * 1024 + threadIdx.x * 4;
    int add = bsums[blockIdx.x];
    #pragma unroll
    for (int i = 0; i < 4; i++)
        if (base + i < n) out[base + i] += add;
}

__global__ void k_selfloop(const int* __restrict__ row_ptr, int* __restrict__ csr_src,
                           int* __restrict__ cursor, int n) {
    int i = blockIdx.x * blockDim.x + threadIdx.x;
    if (i < n) { int rp = row_ptr[i]; csr_src[rp] = i; cursor[i] = rp + 1; }
}

__global__ void k_scatter(const int* __restrict__ src, const int* __restrict__ dst, int E,
                          int* __restrict__ cursor, int* __restrict__ csr_src) {
    int stride = gridDim.x * blockDim.x;
    for (int i = blockIdx.x * blockDim.x + threadIdx.x; i < E; i += stride) {
        int d = dst[i];
        int pos = atomicAdd(&cursor[d], 1);
        csr_src[pos] = src[i];
    }
}

// ---------------- tiled per-layer GEMM: H = act(X) @ W, fused scores ----------------
// block = 64 nodes x 64 features, 4 waves; wave computes 16 nodes, lane = out feature.
template <int FIN, int USE_BN>
__global__ void __launch_bounds__(256) k_gemm(
    const float* __restrict__ X, const float* __restrict__ W,
    const float* __restrict__ a_src, const float* __restrict__ a_dst,
    const float* __restrict__ bn_sc, const float* __restrict__ bn_sh,
    float* __restrict__ H, float* __restrict__ S, float* __restrict__ Dv, int n) {
    __shared__ float Xl[64 * FIN];
    __shared__ float Wl[FIN * 64];
    const int node0 = blockIdx.x * 64;
    const int ROWF4 = FIN / 4;

    // stage W [FIN][64] (coalesced float4)
    {
        const float4* W4 = (const float4*)W;
        float4* Wl4 = (float4*)Wl;
        for (int f = threadIdx.x; f < FIN * 16; f += 256) Wl4[f] = W4[f];
    }
    // stage X tile [64][FIN], fusing BN+ReLU of the previous layer
    {
        const float4* X4 = (const float4*)X;
        float4* Xl4 = (float4*)Xl;
        for (int f = threadIdx.x; f < 64 * ROWF4; f += 256) {
            int r = f / ROWF4, c = f % ROWF4;
            float4 v = make_float4(0.f, 0.f, 0.f, 0.f);
            if (node0 + r < n) v = X4[(size_t)(node0 + r) * ROWF4 + c];
            if (USE_BN) {
                int k = c * 4;
                v.x = fmaxf(fmaf(v.x, bn_sc[k + 0], bn_sh[k + 0]), 0.f);
                v.y = fmaxf(fmaf(v.y, bn_sc[k + 1], bn_sh[k + 1]), 0.f);
                v.z = fmaxf(fmaf(v.z, bn_sc[k + 2], bn_sh[k + 2]), 0.f);
                v.w = fmaxf(fmaf(v.w, bn_sc[k + 3], bn_sh[k + 3]), 0.f);
            }
            Xl4[f] = v;
        }
    }
    __syncthreads();

    const int wave = threadIdx.x >> 6, lane = threadIdx.x & 63;
    const int nbase = wave * 16;
    float acc[16];
    #pragma unroll
    for (int i = 0; i < 16; i++) acc[i] = 0.f;

    const float4* Xl4 = (const float4*)Xl;
    for (int kg = 0; kg < ROWF4; kg++) {
        float w0 = Wl[(kg * 4 + 0) * 64 + lane];
        float w1 = Wl[(kg * 4 + 1) * 64 + lane];
        float w2 = Wl[(kg * 4 + 2) * 64 + lane];
        float w3 = Wl[(kg * 4 + 3) * 64 + lane];
        #pragma unroll
        for (int i = 0; i < 16; i++) {
            float4 xv = Xl4[(nbase + i) * ROWF4 + kg];  // broadcast read
            acc[i] = fmaf(xv.x, w0, acc[i]);
            acc[i] = fmaf(xv.y, w1, acc[i]);
            acc[i] = fmaf(xv.z, w2, acc[i]);
            acc[i] = fmaf(xv.w, w3, acc[i]);
        }
    }

    float asl = a_src[lane], adl = a_dst[lane];
    #pragma unroll
    for (int i = 0; i < 16; i++) {
        int node = node0 + nbase + i;
        if (node < n) {  // wave-uniform branch
            H[(size_t)node * 64 + lane] = acc[i];
            float ps = wave_red_sum(acc[i] * asl);
            float pd = wave_red_sum(acc[i] * adl);
            if (lane == 0) { S[node] = ps; Dv[node] = pd; }
        }
    }
}

// ---------------- node-parallel GAT aggregate, online softmax ----------------
__global__ void __launch_bounds__(256) k_aggregate(
    const float* __restrict__ H, const float* __restrict__ S, const float* __restrict__ Dv,
    const int* __restrict__ row_ptr, const int* __restrict__ csr_src,
    const float* __restrict__ bias, float* __restrict__ out, int n) {
    int wave = threadIdx.x >> 6, lane = threadIdx.x & 63;
    int node = blockIdx.x * 4 + wave;
    if (node >= n) return;
    int start = row_ptr[node], end = row_ptr[node + 1];
    float dn = Dv[node];
    float m = -1e30f, z = 0.f, acc = 0.f;
    for (int base = start; base < end; base += 64) {
        int cnt = min(64, end - base);
        int sj = 0;
        float e = -1e30f;
        if (lane < cnt) {
            sj = csr_src[base + lane];
            float t = S[sj] + dn;
            e = (t > 0.f) ? t : NEG_SLOPE * t;
        }
        float cm = e;
        for (int off = 32; off; off >>= 1) cm = fmaxf(cm, __shfl_xor(cm, off));
        float newm = fmaxf(m, cm);
        float rescale = __expf(m - newm);  // m=-1e30 first pass -> 0
        float w = (lane < cnt) ? __expf(e - newm) : 0.f;
        float ws = w;
        for (int off = 32; off; off >>= 1) ws += __shfl_xor(ws, off);
        z = z * rescale + ws;
        acc *= rescale;
        for (int jj = 0; jj < cnt; jj++) {
            float wj = __shfl(w, jj);
            int sjj = __shfl(sj, jj);
            acc = fmaf(wj, H[(size_t)sjj * 64 + lane], acc);
        }
        m = newm;
    }
    out[(size_t)node * 64 + lane] = acc / z + bias[lane];
}

// ---------------- batchnorm stats ----------------
__global__ void k_zero_stats(float* stats) {
    if (threadIdx.x < 128) stats[threadIdx.x] = 0.f;
}

__global__ void __launch_bounds__(256) k_colstats(const float* __restrict__ T, int n,
                                                  float* __restrict__ sums,
                                                  float* __restrict__ sumsq) {
    __shared__ float ls[256], lq[256];
    int f = threadIdx.x & 63;
    int rowgrp = threadIdx.x >> 6;
    float s = 0.f, q = 0.f;
    for (int r = blockIdx.x * 4 + rowgrp; r < n; r += gridDim.x * 4) {
        float v = T[(size_t)r * 64 + f];
        s += v;
        q += v * v;
    }
    ls[threadIdx.x] = s; lq[threadIdx.x] = q;
    __syncthreads();
    if (threadIdx.x < 128) {
        ls[threadIdx.x] += ls[threadIdx.x + 128];
        lq[threadIdx.x] += lq[threadIdx.x + 128];
    }
    __syncthreads();
    if (threadIdx.x < 64) {
        atomicAdd(&sums[f], ls[threadIdx.x] + ls[threadIdx.x + 64]);
        atomicAdd(&sumsq[f], lq[threadIdx.x] + lq[threadIdx.x + 64]);
    }
}

__global__ void k_bn_finalize(const float* __restrict__ sums, const float* __restrict__ sumsq,
                              const float* __restrict__ g, const float* __restrict__ be,
                              int n, float* __restrict__ sc, float* __restrict__ sh) {
    int f = threadIdx.x;
    if (f < 64) {
        float inv_n = 1.f / (float)n;
        float mu = sums[f] * inv_n;
        float var = sumsq[f] * inv_n - mu * mu;
        float rstd = rsqrtf(var + BN_EPS);
        float scale = rstd * g[f];
        sc[f] = scale;
        sh[f] = be[f] - mu * scale;
    }
}

extern "C" void kernel_launch(void* const* d_in, const int* in_sizes, int n_in,
                              void* d_out, int out_size, void* d_ws, size_t ws_size,
                              hipStream_t stream) {
    const float* x        = (const float*)d_in[0];
    const int*   ei       = (const int*)d_in[1];
    const float* W_in     = (const float*)d_in[2];
    const float* a_src_in = (const float*)d_in[3];
    const float* a_dst_in = (const float*)d_in[4];
    const float* b_in     = (const float*)d_in[5];
    const float* W_mid    = (const float*)d_in[6];
    const float* a_src_mid= (const float*)d_in[7];
    const float* a_dst_mid= (const float*)d_in[8];
    const float* b_mid    = (const float*)d_in[9];
    const float* gamma    = (const float*)d_in[10];
    const float* beta     = (const float*)d_in[11];
    const float* W_out    = (const float*)d_in[12];
    const float* a_src_out= (const float*)d_in[13];
    const float* a_dst_out= (const float*)d_in[14];
    const float* b_out    = (const float*)d_in[15];

    int n = in_sizes[0] / 128;   // 50000
    int E = in_sizes[1] / 2;     // 1250000
    const int* srcE = ei;
    const int* dstE = ei + E;

    auto alignup = [](size_t v) { return (v + 255) & ~(size_t)255; };
    char* p = (char*)d_ws;
    int* counts  = (int*)p; p += alignup((size_t)n * 4);
    int* row_ptr = (int*)p; p += alignup((size_t)(n + 1) * 4);
    int nb = (n + 1023) / 1024;
    int* bsums   = (int*)p; p += alignup((size_t)nb * 4);
    int* cursor  = (int*)p; p += alignup((size_t)n * 4);
    int* csr     = (int*)p; p += alignup((size_t)(E + n) * 4);
    float* H     = (float*)p; p += alignup((size_t)n * 64 * 4);
    float* S     = (float*)p; p += alignup((size_t)n * 4);
    float* Dv    = (float*)p; p += alignup((size_t)n * 4);
    float* stats = (float*)p; p += alignup(128 * 4);
    float* bnsc  = (float*)p; p += alignup(64 * 4);
    float* bnsh  = (float*)p; p += alignup(64 * 4);
    float* T     = (float*)d_out;  // layer ping buffer; final aggregate rewrites it

    // ---- CSR build (edges identical across all 5 layers) ----
    k_init_counts<<<(n + 255) / 256, 256, 0, stream>>>(counts, n);
    k_hist<<<2048, 256, 0, stream>>>(dstE, E, counts);
    k_scan_block<<<nb, 256, 0, stream>>>(counts, row_ptr, bsums, n);
    k_scan_bsums<<<1, 64, 0, stream>>>(bsums, nb, row_ptr + n);
    k_scan_add<<<nb, 256, 0, stream>>>(row_ptr, bsums, n);
    k_selfloop<<<(n + 255) / 256, 256, 0, stream>>>(row_ptr, csr, cursor, n);
    k_scatter<<<2048, 256, 0, stream>>>(srcE, dstE, E, cursor, csr);

    int gb = (n + 3) / 4;        // aggregate grid (4 nodes/block)
    int gg = (n + 63) / 64;      // gemm grid (64 nodes/block)

    // ---- input GAT layer ----
    k_gemm<128, 0><<<gg, 256, 0, stream>>>(x, W_in, a_src_in, a_dst_in, nullptr, nullptr,
                                           H, S, Dv, n);
    k_aggregate<<<gb, 256, 0, stream>>>(H, S, Dv, row_ptr, csr, b_in, T, n);

    // ---- mid layers: gat -> BN stats; BN+ReLU fused into next gemm's input ----
    for (int l = 0; l < 3; l++) {
        if (l == 0)
            k_gemm<64, 0><<<gg, 256, 0, stream>>>(T, W_mid + l * 4096, a_src_mid + l * 64,
                                                  a_dst_mid + l * 64, nullptr, nullptr,
                                                  H, S, Dv, n);
        else
            k_gemm<64, 1><<<gg, 256, 0, stream>>>(T, W_mid + l * 4096, a_src_mid + l * 64,
                                                  a_dst_mid + l * 64, bnsc, bnsh,
                                                  H, S, Dv, n);
        k_aggregate<<<gb, 256, 0, stream>>>(H, S, Dv, row_ptr, csr, b_mid + l * 64, T, n);
        k_zero_stats<<<1, 128, 0, stream>>>(stats);
        k_colstats<<<512, 256, 0, stream>>>(T, n, stats, stats + 64);
        k_bn_finalize<<<1, 64, 0, stream>>>(stats, stats + 64, gamma + l * 64, beta + l * 64,
                                            n, bnsc, bnsh);
    }

    // ---- output GAT layer (consumes BN+ReLU of last mid layer) ----
    k_gemm<64, 1><<<gg, 256, 0, stream>>>(T, W_out, a_src_out, a_dst_out, bnsc, bnsh,
                                          H, S, Dv, n);
    k_aggregate<<<gb, 256, 0, stream>>>(H, S, Dv, row_ptr, csr, b_out, (float*)d_out, n);
}

// Round 3
// 593.589 us; speedup vs baseline: 1.5182x; 1.3507x over previous
//
#include <hip/hip_runtime.h>
#include <math.h>

#define NEG_SLOPE 0.2f
#define BN_EPS 1e-5f

static __device__ __forceinline__ float wave_red_sum(float v) {
    for (int off = 32; off; off >>= 1) v += __shfl_xor(v, off);
    return v;
}

// ---------------- CSR build ----------------
__global__ void k_init_counts(int* counts, int n) {
    int i = blockIdx.x * blockDim.x + threadIdx.x;
    if (i < n) counts[i] = 1;  // self-loop reserved
}

__global__ void k_hist(const int* __restrict__ dst, int E4, int* __restrict__ counts) {
    int stride = gridDim.x * blockDim.x;
    const int4* d4 = (const int4*)dst;
    for (int i = blockIdx.x * blockDim.x + threadIdx.x; i < E4; i += stride) {
        int4 v = d4[i];
        atomicAdd(&counts[v.x], 1);
        atomicAdd(&counts[v.y], 1);
        atomicAdd(&counts[v.z], 1);
        atomicAdd(&counts[v.w], 1);
    }
}

// exclusive scan, 1024 elems/block (256 thr x 4)
__global__ void k_scan_block(const int* __restrict__ in, int* __restrict__ out,
                             int* __restrict__ bsums, int n) {
    __shared__ int lds[256];
    int tid = threadIdx.x;
    int base = blockIdx.x * 1024 + tid * 4;
    int v0 = 0, v1 = 0, v2 = 0, v3 = 0;
    if (base + 0 < n) v0 = in[base + 0];
    if (base + 1 < n) v1 = in[base + 1];
    if (base + 2 < n) v2 = in[base + 2];
    if (base + 3 < n) v3 = in[base + 3];
    int s = v0 + v1 + v2 + v3;
    lds[tid] = s;
    __syncthreads();
    for (int off = 1; off < 256; off <<= 1) {
        int t = (tid >= off) ? lds[tid - off] : 0;
        __syncthreads();
        lds[tid] += t;
        __syncthreads();
    }
    int excl = lds[tid] - s;
    if (base + 0 < n) out[base + 0] = excl; excl += v0;
    if (base + 1 < n) out[base + 1] = excl; excl += v1;
    if (base + 2 < n) out[base + 2] = excl; excl += v2;
    if (base + 3 < n) out[base + 3] = excl;
    if (tid == 255) bsums[blockIdx.x] = lds[255];
}

__global__ void k_scan_bsums(int* bsums, int nb, int* total) {
    if (threadIdx.x == 0 && blockIdx.x == 0) {
        int run = 0;
        for (int i = 0; i < nb; i++) { int t = bsums[i]; bsums[i] = run; run += t; }
        *total = run;
    }
}

__global__ void k_scan_add(int* __restrict__ out, const int* __restrict__ bsums, int n) {
    int base = blockIdx.x * 1024 + threadIdx.x * 4;
    int add = bsums[blockIdx.x];
    #pragma unroll
    for (int i = 0; i < 4; i++)
        if (base + i < n) out[base + i] += add;
}

__global__ void k_selfloop(const int* __restrict__ row_ptr, int* __restrict__ csr_src,
                           int* __restrict__ cursor, int n) {
    int i = blockIdx.x * blockDim.x + threadIdx.x;
    if (i < n) { int rp = row_ptr[i]; csr_src[rp] = i; cursor[i] = rp + 1; }
}

__global__ void k_scatter(const int* __restrict__ src, const int* __restrict__ dst, int E4,
                          int* __restrict__ cursor, int* __restrict__ csr_src) {
    int stride = gridDim.x * blockDim.x;
    const int4* s4 = (const int4*)src;
    const int4* d4 = (const int4*)dst;
    for (int i = blockIdx.x * blockDim.x + threadIdx.x; i < E4; i += stride) {
        int4 s = s4[i];
        int4 d = d4[i];
        csr_src[atomicAdd(&cursor[d.x], 1)] = s.x;
        csr_src[atomicAdd(&cursor[d.y], 1)] = s.y;
        csr_src[atomicAdd(&cursor[d.z], 1)] = s.z;
        csr_src[atomicAdd(&cursor[d.w], 1)] = s.w;
    }
}

// ---------------- tiled per-layer GEMM: H = act(X) @ W, fused scores ----------------
// block = 64 nodes x 64 features, 4 waves; wave computes 16 nodes, lane = out feature.
template <int FIN, int USE_BN>
__global__ void __launch_bounds__(256) k_gemm(
    const float* __restrict__ X, const float* __restrict__ W,
    const float* __restrict__ a_src, const float* __restrict__ a_dst,
    const float* __restrict__ bn_sc, const float* __restrict__ bn_sh,
    float* __restrict__ H, float* __restrict__ S, float* __restrict__ Dv, int n) {
    __shared__ float Xl[64 * FIN];
    __shared__ float Wl[FIN * 64];
    const int node0 = blockIdx.x * 64;
    const int ROWF4 = FIN / 4;

    // stage W [FIN][64] (coalesced float4)
    {
        const float4* W4 = (const float4*)W;
        float4* Wl4 = (float4*)Wl;
        for (int f = threadIdx.x; f < FIN * 16; f += 256) Wl4[f] = W4[f];
    }
    // stage X tile [64][FIN], fusing BN+ReLU of the previous layer
    {
        const float4* X4 = (const float4*)X;
        float4* Xl4 = (float4*)Xl;
        for (int f = threadIdx.x; f < 64 * ROWF4; f += 256) {
            int r = f / ROWF4, c = f % ROWF4;
            float4 v = make_float4(0.f, 0.f, 0.f, 0.f);
            if (node0 + r < n) v = X4[(size_t)(node0 + r) * ROWF4 + c];
            if (USE_BN) {
                int k = c * 4;
                v.x = fmaxf(fmaf(v.x, bn_sc[k + 0], bn_sh[k + 0]), 0.f);
                v.y = fmaxf(fmaf(v.y, bn_sc[k + 1], bn_sh[k + 1]), 0.f);
                v.z = fmaxf(fmaf(v.z, bn_sc[k + 2], bn_sh[k + 2]), 0.f);
                v.w = fmaxf(fmaf(v.w, bn_sc[k + 3], bn_sh[k + 3]), 0.f);
            }
            Xl4[f] = v;
        }
    }
    __syncthreads();

    const int wave = threadIdx.x >> 6, lane = threadIdx.x & 63;
    const int nbase = wave * 16;
    float acc[16];
    #pragma unroll
    for (int i = 0; i < 16; i++) acc[i] = 0.f;

    const float4* Xl4 = (const float4*)Xl;
    for (int kg = 0; kg < ROWF4; kg++) {
        float w0 = Wl[(kg * 4 + 0) * 64 + lane];
        float w1 = Wl[(kg * 4 + 1) * 64 + lane];
        float w2 = Wl[(kg * 4 + 2) * 64 + lane];
        float w3 = Wl[(kg * 4 + 3) * 64 + lane];
        #pragma unroll
        for (int i = 0; i < 16; i++) {
            float4 xv = Xl4[(nbase + i) * ROWF4 + kg];  // broadcast read
            acc[i] = fmaf(xv.x, w0, acc[i]);
            acc[i] = fmaf(xv.y, w1, acc[i]);
            acc[i] = fmaf(xv.z, w2, acc[i]);
            acc[i] = fmaf(xv.w, w3, acc[i]);
        }
    }

    float asl = a_src[lane], adl = a_dst[lane];
    #pragma unroll
    for (int i = 0; i < 16; i++) {
        int node = node0 + nbase + i;
        if (node < n) {  // wave-uniform branch
            H[(size_t)node * 64 + lane] = acc[i];
            float ps = wave_red_sum(acc[i] * asl);
            float pd = wave_red_sum(acc[i] * adl);
            if (lane == 0) { S[node] = ps; Dv[node] = pd; }
        }
    }
}

// ---------------- node-parallel GAT aggregate ----------------
// alpha = exp(e)/sum(exp(e)) computed WITHOUT max-subtraction (identical math;
// e bounded ~|8| by data scale). Per-lane z accumulation, one reduction at end.
// 4-way unrolled gather loop with independent accumulators for MLP.
__global__ void __launch_bounds__(256) k_aggregate(
    const float* __restrict__ H, const float* __restrict__ S, const float* __restrict__ Dv,
    const int* __restrict__ row_ptr, const int* __restrict__ csr_src,
    const float* __restrict__ bias, float* __restrict__ out, int n) {
    int wave = threadIdx.x >> 6, lane = threadIdx.x & 63;
    int node = blockIdx.x * 4 + wave;
    if (node >= n) return;
    int start = row_ptr[node], end = row_ptr[node + 1];
    float dn = Dv[node];
    float acc0 = 0.f, acc1 = 0.f, acc2 = 0.f, acc3 = 0.f;
    float zlane = 0.f;
    for (int base = start; base < end; base += 64) {
        int cnt = min(64, end - base);
        int sj = 0;
        float w = 0.f;
        if (lane < cnt) {
            sj = csr_src[base + lane];
            float t = S[sj] + dn;
            t = (t > 0.f) ? t : NEG_SLOPE * t;
            w = __expf(t);
        }
        zlane += w;
        int jj = 0;
        for (; jj + 4 <= cnt; jj += 4) {
            float w0 = __shfl(w, jj + 0), w1 = __shfl(w, jj + 1);
            float w2 = __shfl(w, jj + 2), w3 = __shfl(w, jj + 3);
            int s0 = __shfl(sj, jj + 0), s1 = __shfl(sj, jj + 1);
            int s2 = __shfl(sj, jj + 2), s3 = __shfl(sj, jj + 3);
            float h0 = H[(size_t)s0 * 64 + lane];
            float h1 = H[(size_t)s1 * 64 + lane];
            float h2 = H[(size_t)s2 * 64 + lane];
            float h3 = H[(size_t)s3 * 64 + lane];
            acc0 = fmaf(w0, h0, acc0);
            acc1 = fmaf(w1, h1, acc1);
            acc2 = fmaf(w2, h2, acc2);
            acc3 = fmaf(w3, h3, acc3);
        }
        for (; jj < cnt; jj++) {
            float wj = __shfl(w, jj);
            int sjj = __shfl(sj, jj);
            acc0 = fmaf(wj, H[(size_t)sjj * 64 + lane], acc0);
        }
    }
    float z = wave_red_sum(zlane);
    float acc = (acc0 + acc1) + (acc2 + acc3);
    out[(size_t)node * 64 + lane] = acc / z + bias[lane];
}

// ---------------- batchnorm stats ----------------
__global__ void k_zero_stats(float* stats) {
    if (threadIdx.x < 128) stats[threadIdx.x] = 0.f;
}

__global__ void __launch_bounds__(256) k_colstats(const float* __restrict__ T, int n,
                                                  float* __restrict__ sums,
                                                  float* __restrict__ sumsq) {
    __shared__ float ls[256], lq[256];
    int f = threadIdx.x & 63;
    int rowgrp = threadIdx.x >> 6;
    float s = 0.f, q = 0.f;
    for (int r = blockIdx.x * 4 + rowgrp; r < n; r += gridDim.x * 4) {
        float v = T[(size_t)r * 64 + f];
        s += v;
        q += v * v;
    }
    ls[threadIdx.x] = s; lq[threadIdx.x] = q;
    __syncthreads();
    if (threadIdx.x < 128) {
        ls[threadIdx.x] += ls[threadIdx.x + 128];
        lq[threadIdx.x] += lq[threadIdx.x + 128];
    }
    __syncthreads();
    if (threadIdx.x < 64) {
        atomicAdd(&sums[f], ls[threadIdx.x] + ls[threadIdx.x + 64]);
        atomicAdd(&sumsq[f], lq[threadIdx.x] + lq[threadIdx.x + 64]);
    }
}

__global__ void k_bn_finalize(const float* __restrict__ sums, const float* __restrict__ sumsq,
                              const float* __restrict__ g, const float* __restrict__ be,
                              int n, float* __restrict__ sc, float* __restrict__ sh) {
    int f = threadIdx.x;
    if (f < 64) {
        float inv_n = 1.f / (float)n;
        float mu = sums[f] * inv_n;
        float var = sumsq[f] * inv_n - mu * mu;
        float rstd = rsqrtf(var + BN_EPS);
        float scale = rstd * g[f];
        sc[f] = scale;
        sh[f] = be[f] - mu * scale;
    }
}

extern "C" void kernel_launch(void* const* d_in, const int* in_sizes, int n_in,
                              void* d_out, int out_size, void* d_ws, size_t ws_size,
                              hipStream_t stream) {
    const float* x        = (const float*)d_in[0];
    const int*   ei       = (const int*)d_in[1];
    const float* W_in     = (const float*)d_in[2];
    const float* a_src_in = (const float*)d_in[3];
    const float* a_dst_in = (const float*)d_in[4];
    const float* b_in     = (const float*)d_in[5];
    const float* W_mid    = (const float*)d_in[6];
    const float* a_src_mid= (const float*)d_in[7];
    const float* a_dst_mid= (const float*)d_in[8];
    const float* b_mid    = (const float*)d_in[9];
    const float* gamma    = (const float*)d_in[10];
    const float* beta     = (const float*)d_in[11];
    const float* W_out    = (const float*)d_in[12];
    const float* a_src_out= (const float*)d_in[13];
    const float* a_dst_out= (const float*)d_in[14];
    const float* b_out    = (const float*)d_in[15];

    int n = in_sizes[0] / 128;   // 50000
    int E = in_sizes[1] / 2;     // 1250000
    const int* srcE = ei;
    const int* dstE = ei + E;

    auto alignup = [](size_t v) { return (v + 255) & ~(size_t)255; };
    char* p = (char*)d_ws;
    int* counts  = (int*)p; p += alignup((size_t)n * 4);
    int* row_ptr = (int*)p; p += alignup((size_t)(n + 1) * 4);
    int nb = (n + 1023) / 1024;
    int* bsums   = (int*)p; p += alignup((size_t)nb * 4);
    int* cursor  = (int*)p; p += alignup((size_t)n * 4);
    int* csr     = (int*)p; p += alignup((size_t)(E + n) * 4);
    float* H     = (float*)p; p += alignup((size_t)n * 64 * 4);
    float* S     = (float*)p; p += alignup((size_t)n * 4);
    float* Dv    = (float*)p; p += alignup((size_t)n * 4);
    float* stats = (float*)p; p += alignup(128 * 4);
    float* bnsc  = (float*)p; p += alignup(64 * 4);
    float* bnsh  = (float*)p; p += alignup(64 * 4);
    float* T     = (float*)d_out;  // layer ping buffer; final aggregate rewrites it

    // ---- CSR build (edges identical across all 5 layers) ----
    k_init_counts<<<(n + 255) / 256, 256, 0, stream>>>(counts, n);
    k_hist<<<1024, 256, 0, stream>>>(dstE, E / 4, counts);
    k_scan_block<<<nb, 256, 0, stream>>>(counts, row_ptr, bsums, n);
    k_scan_bsums<<<1, 64, 0, stream>>>(bsums, nb, row_ptr + n);
    k_scan_add<<<nb, 256, 0, stream>>>(row_ptr, bsums, n);
    k_selfloop<<<(n + 255) / 256, 256, 0, stream>>>(row_ptr, csr, cursor, n);
    k_scatter<<<1024, 256, 0, stream>>>(srcE, dstE, E / 4, cursor, csr);

    int gb = (n + 3) / 4;        // aggregate grid (4 nodes/block)
    int gg = (n + 63) / 64;      // gemm grid (64 nodes/block)

    // ---- input GAT layer ----
    k_gemm<128, 0><<<gg, 256, 0, stream>>>(x, W_in, a_src_in, a_dst_in, nullptr, nullptr,
                                           H, S, Dv, n);
    k_aggregate<<<gb, 256, 0, stream>>>(H, S, Dv, row_ptr, csr, b_in, T, n);

    // ---- mid layers: gat -> BN stats; BN+ReLU fused into next gemm's input ----
    for (int l = 0; l < 3; l++) {
        if (l == 0)
            k_gemm<64, 0><<<gg, 256, 0, stream>>>(T, W_mid + l * 4096, a_src_mid + l * 64,
                                                  a_dst_mid + l * 64, nullptr, nullptr,
                                                  H, S, Dv, n);
        else
            k_gemm<64, 1><<<gg, 256, 0, stream>>>(T, W_mid + l * 4096, a_src_mid + l * 64,
                                                  a_dst_mid + l * 64, bnsc, bnsh,
                                                  H, S, Dv, n);
        k_aggregate<<<gb, 256, 0, stream>>>(H, S, Dv, row_ptr, csr, b_mid + l * 64, T, n);
        k_zero_stats<<<1, 128, 0, stream>>>(stats);
        k_colstats<<<512, 256, 0, stream>>>(T, n, stats, stats + 64);
        k_bn_finalize<<<1, 64, 0, stream>>>(stats, stats + 64, gamma + l * 64, beta + l * 64,
                                            n, bnsc, bnsh);
    }

    // ---- output GAT layer (consumes BN+ReLU of last mid layer) ----
    k_gemm<64, 1><<<gg, 256, 0, stream>>>(T, W_out, a_src_out, a_dst_out, bnsc, bnsh,
                                          H, S, Dv, n);
    k_aggregate<<<gb, 256, 0, stream>>>(H, S, Dv, row_ptr, csr, b_out, (float*)d_out, n);
}

// Round 4
// 565.404 us; speedup vs baseline: 1.5939x; 1.0498x over previous
//
#include <hip/hip_runtime.h>
#include <math.h>

#define NEG_SLOPE 0.2f
#define BN_EPS 1e-5f

static __device__ __forceinline__ float wave_red_sum(float v) {
    for (int off = 32; off; off >>= 1) v += __shfl_xor(v, off);
    return v;
}

// fp32 -> bf16 bits, round-to-nearest-even
static __device__ __forceinline__ unsigned short f2bf(float f) {
    unsigned int u = __float_as_uint(f);
    unsigned int r = u + 0x7FFFu + ((u >> 16) & 1u);
    return (unsigned short)(r >> 16);
}

// ---------------- CSR build ----------------
__global__ void k_init_counts(int* counts, int n) {
    int i = blockIdx.x * blockDim.x + threadIdx.x;
    if (i < n) counts[i] = 1;  // self-loop reserved
}

__global__ void k_hist(const int* __restrict__ dst, int E4, int* __restrict__ counts) {
    int stride = gridDim.x * blockDim.x;
    const int4* d4 = (const int4*)dst;
    for (int i = blockIdx.x * blockDim.x + threadIdx.x; i < E4; i += stride) {
        int4 v = d4[i];
        atomicAdd(&counts[v.x], 1);
        atomicAdd(&counts[v.y], 1);
        atomicAdd(&counts[v.z], 1);
        atomicAdd(&counts[v.w], 1);
    }
}

// exclusive scan, 1024 elems/block (256 thr x 4)
__global__ void k_scan_block(const int* __restrict__ in, int* __restrict__ out,
                             int* __restrict__ bsums, int n) {
    __shared__ int lds[256];
    int tid = threadIdx.x;
    int base = blockIdx.x * 1024 + tid * 4;
    int v0 = 0, v1 = 0, v2 = 0, v3 = 0;
    if (base + 0 < n) v0 = in[base + 0];
    if (base + 1 < n) v1 = in[base + 1];
    if (base + 2 < n) v2 = in[base + 2];
    if (base + 3 < n) v3 = in[base + 3];
    int s = v0 + v1 + v2 + v3;
    lds[tid] = s;
    __syncthreads();
    for (int off = 1; off < 256; off <<= 1) {
        int t = (tid >= off) ? lds[tid - off] : 0;
        __syncthreads();
        lds[tid] += t;
        __syncthreads();
    }
    int excl = lds[tid] - s;
    if (base + 0 < n) out[base + 0] = excl; excl += v0;
    if (base + 1 < n) out[base + 1] = excl; excl += v1;
    if (base + 2 < n) out[base + 2] = excl; excl += v2;
    if (base + 3 < n) out[base + 3] = excl;
    if (tid == 255) bsums[blockIdx.x] = lds[255];
}

__global__ void k_scan_bsums(int* bsums, int nb, int* total) {
    if (threadIdx.x == 0 && blockIdx.x == 0) {
        int run = 0;
        for (int i = 0; i < nb; i++) { int t = bsums[i]; bsums[i] = run; run += t; }
        *total = run;
    }
}

__global__ void k_scan_add(int* __restrict__ out, const int* __restrict__ bsums, int n) {
    int base = blockIdx.x * 1024 + threadIdx.x * 4;
    int add = bsums[blockIdx.x];
    #pragma unroll
    for (int i = 0; i < 4; i++)
        if (base + i < n) out[base + i] += add;
}

__global__ void k_selfloop(const int* __restrict__ row_ptr, int* __restrict__ csr_src,
                           int* __restrict__ cursor, int n) {
    int i = blockIdx.x * blockDim.x + threadIdx.x;
    if (i < n) { int rp = row_ptr[i]; csr_src[rp] = i; cursor[i] = rp + 1; }
}

__global__ void k_scatter(const int* __restrict__ src, const int* __restrict__ dst, int E4,
                          int* __restrict__ cursor, int* __restrict__ csr_src) {
    int stride = gridDim.x * blockDim.x;
    const int4* s4 = (const int4*)src;
    const int4* d4 = (const int4*)dst;
    for (int i = blockIdx.x * blockDim.x + threadIdx.x; i < E4; i += stride) {
        int4 s = s4[i];
        int4 d = d4[i];
        csr_src[atomicAdd(&cursor[d.x], 1)] = s.x;
        csr_src[atomicAdd(&cursor[d.y], 1)] = s.y;
        csr_src[atomicAdd(&cursor[d.z], 1)] = s.z;
        csr_src[atomicAdd(&cursor[d.w], 1)] = s.w;
    }
}

// ---------------- tiled per-layer GEMM: H(bf16) = act(X) @ W, fused scores ----------------
// block = 64 nodes x 64 features, 4 waves; wave computes 16 nodes, lane = out feature.
// H stored as bf16 [n][64]; scores S/D computed from fp32 registers (exact path).
template <int FIN, int USE_BN>
__global__ void __launch_bounds__(256) k_gemm(
    const float* __restrict__ X, const float* __restrict__ W,
    const float* __restrict__ a_src, const float* __restrict__ a_dst,
    const float* __restrict__ bn_sc, const float* __restrict__ bn_sh,
    unsigned short* __restrict__ H16, float* __restrict__ S, float* __restrict__ Dv, int n) {
    __shared__ float Xl[64 * FIN];
    __shared__ float Wl[FIN * 64];
    const int node0 = blockIdx.x * 64;
    const int ROWF4 = FIN / 4;

    // stage W [FIN][64] (coalesced float4)
    {
        const float4* W4 = (const float4*)W;
        float4* Wl4 = (float4*)Wl;
        for (int f = threadIdx.x; f < FIN * 16; f += 256) Wl4[f] = W4[f];
    }
    // stage X tile [64][FIN], fusing BN+ReLU of the previous layer
    {
        const float4* X4 = (const float4*)X;
        float4* Xl4 = (float4*)Xl;
        for (int f = threadIdx.x; f < 64 * ROWF4; f += 256) {
            int r = f / ROWF4, c = f % ROWF4;
            float4 v = make_float4(0.f, 0.f, 0.f, 0.f);
            if (node0 + r < n) v = X4[(size_t)(node0 + r) * ROWF4 + c];
            if (USE_BN) {
                int k = c * 4;
                v.x = fmaxf(fmaf(v.x, bn_sc[k + 0], bn_sh[k + 0]), 0.f);
                v.y = fmaxf(fmaf(v.y, bn_sc[k + 1], bn_sh[k + 1]), 0.f);
                v.z = fmaxf(fmaf(v.z, bn_sc[k + 2], bn_sh[k + 2]), 0.f);
                v.w = fmaxf(fmaf(v.w, bn_sc[k + 3], bn_sh[k + 3]), 0.f);
            }
            Xl4[f] = v;
        }
    }
    __syncthreads();

    const int wave = threadIdx.x >> 6, lane = threadIdx.x & 63;
    const int nbase = wave * 16;
    float acc[16];
    #pragma unroll
    for (int i = 0; i < 16; i++) acc[i] = 0.f;

    const float4* Xl4 = (const float4*)Xl;
    for (int kg = 0; kg < ROWF4; kg++) {
        float w0 = Wl[(kg * 4 + 0) * 64 + lane];
        float w1 = Wl[(kg * 4 + 1) * 64 + lane];
        float w2 = Wl[(kg * 4 + 2) * 64 + lane];
        float w3 = Wl[(kg * 4 + 3) * 64 + lane];
        #pragma unroll
        for (int i = 0; i < 16; i++) {
            float4 xv = Xl4[(nbase + i) * ROWF4 + kg];  // broadcast read
            acc[i] = fmaf(xv.x, w0, acc[i]);
            acc[i] = fmaf(xv.y, w1, acc[i]);
            acc[i] = fmaf(xv.z, w2, acc[i]);
            acc[i] = fmaf(xv.w, w3, acc[i]);
        }
    }

    float asl = a_src[lane], adl = a_dst[lane];
    #pragma unroll
    for (int i = 0; i < 16; i++) {
        int node = node0 + nbase + i;
        if (node < n) {  // wave-uniform branch
            H16[(size_t)node * 64 + lane] = f2bf(acc[i]);
            float ps = wave_red_sum(acc[i] * asl);
            float pd = wave_red_sum(acc[i] * adl);
            if (lane == 0) { S[node] = ps; Dv[node] = pd; }
        }
    }
}

// ---------------- node-parallel GAT aggregate (bf16 H gather) ----------------
// wave = 1 node. Softmax weights per lane (edge) in fp32; gather phase: each
// half-wave handles one edge, lane reads 1 uint = 2 packed bf16 features
// -> 128B coalesced per edge, 2 loads in flight per iteration.
// Branchless tail: lanes >= cnt carry w=0, min(idx,63) shfl lands on such a lane.
__global__ void __launch_bounds__(256) k_aggregate(
    const unsigned int* __restrict__ H2, const float* __restrict__ S,
    const float* __restrict__ Dv,
    const int* __restrict__ row_ptr, const int* __restrict__ csr_src,
    const float* __restrict__ bias, float* __restrict__ out, int n) {
    int wave = threadIdx.x >> 6, lane = threadIdx.x & 63;
    int node = blockIdx.x * 4 + wave;
    if (node >= n) return;
    int start = row_ptr[node], end = row_ptr[node + 1];
    float dn = Dv[node];
    int half = lane >> 5;
    int col = lane & 31;
    float accL0 = 0.f, accH0 = 0.f, accL1 = 0.f, accH1 = 0.f;
    float zlane = 0.f;
    for (int base = start; base < end; base += 64) {
        int cnt = min(64, end - base);
        int sj = 0;
        float w = 0.f;
        if (lane < cnt) {
            sj = csr_src[base + lane];
            float t = S[sj] + dn;
            t = (t > 0.f) ? t : NEG_SLOPE * t;
            w = __expf(t);
        }
        zlane += w;
        for (int jj = 0; jj < cnt; jj += 4) {
            int i0 = min(jj + half, 63);
            int i1 = min(jj + 2 + half, 63);
            float w0 = __shfl(w, i0);   // 0 when index >= cnt
            float w1 = __shfl(w, i1);
            int s0 = __shfl(sj, i0);
            int s1 = __shfl(sj, i1);
            unsigned int u0 = H2[(size_t)s0 * 32 + col];
            unsigned int u1 = H2[(size_t)s1 * 32 + col];
            float l0 = __uint_as_float(u0 << 16);
            float h0 = __uint_as_float(u0 & 0xFFFF0000u);
            float l1 = __uint_as_float(u1 << 16);
            float h1 = __uint_as_float(u1 & 0xFFFF0000u);
            accL0 = fmaf(w0, l0, accL0);
            accH0 = fmaf(w0, h0, accH0);
            accL1 = fmaf(w1, l1, accL1);
            accH1 = fmaf(w1, h1, accH1);
        }
    }
    float z = wave_red_sum(zlane);
    float accL = accL0 + accL1;
    float accH = accH0 + accH1;
    accL += __shfl_xor(accL, 32);
    accH += __shfl_xor(accH, 32);
    if (half == 0) {
        float2 b2 = ((const float2*)bias)[col];
        float2 o;
        o.x = accL / z + b2.x;
        o.y = accH / z + b2.y;
        ((float2*)out)[(size_t)node * 32 + col] = o;
    }
}

// ---------------- batchnorm stats ----------------
__global__ void k_zero_stats(float* stats) {
    if (threadIdx.x < 128) stats[threadIdx.x] = 0.f;
}

__global__ void __launch_bounds__(256) k_colstats(const float* __restrict__ T, int n,
                                                  float* __restrict__ sums,
                                                  float* __restrict__ sumsq) {
    __shared__ float ls[256], lq[256];
    int f = threadIdx.x & 63;
    int rowgrp = threadIdx.x >> 6;
    float s = 0.f, q = 0.f;
    for (int r = blockIdx.x * 4 + rowgrp; r < n; r += gridDim.x * 4) {
        float v = T[(size_t)r * 64 + f];
        s += v;
        q += v * v;
    }
    ls[threadIdx.x] = s; lq[threadIdx.x] = q;
    __syncthreads();
    if (threadIdx.x < 128) {
        ls[threadIdx.x] += ls[threadIdx.x + 128];
        lq[threadIdx.x] += lq[threadIdx.x + 128];
    }
    __syncthreads();
    if (threadIdx.x < 64) {
        atomicAdd(&sums[f], ls[threadIdx.x] + ls[threadIdx.x + 64]);
        atomicAdd(&sumsq[f], lq[threadIdx.x] + lq[threadIdx.x + 64]);
    }
}

__global__ void k_bn_finalize(const float* __restrict__ sums, const float* __restrict__ sumsq,
                              const float* __restrict__ g, const float* __restrict__ be,
                              int n, float* __restrict__ sc, float* __restrict__ sh) {
    int f = threadIdx.x;
    if (f < 64) {
        float inv_n = 1.f / (float)n;
        float mu = sums[f] * inv_n;
        float var = sumsq[f] * inv_n - mu * mu;
        float rstd = rsqrtf(var + BN_EPS);
        float scale = rstd * g[f];
        sc[f] = scale;
        sh[f] = be[f] - mu * scale;
    }
}

extern "C" void kernel_launch(void* const* d_in, const int* in_sizes, int n_in,
                              void* d_out, int out_size, void* d_ws, size_t ws_size,
                              hipStream_t stream) {
    const float* x        = (const float*)d_in[0];
    const int*   ei       = (const int*)d_in[1];
    const float* W_in     = (const float*)d_in[2];
    const float* a_src_in = (const float*)d_in[3];
    const float* a_dst_in = (const float*)d_in[4];
    const float* b_in     = (const float*)d_in[5];
    const float* W_mid    = (const float*)d_in[6];
    const float* a_src_mid= (const float*)d_in[7];
    const float* a_dst_mid= (const float*)d_in[8];
    const float* b_mid    = (const float*)d_in[9];
    const float* gamma    = (const float*)d_in[10];
    const float* beta     = (const float*)d_in[11];
    const float* W_out    = (const float*)d_in[12];
    const float* a_src_out= (const float*)d_in[13];
    const float* a_dst_out= (const float*)d_in[14];
    const float* b_out    = (const float*)d_in[15];

    int n = in_sizes[0] / 128;   // 50000
    int E = in_sizes[1] / 2;     // 1250000
    const int* srcE = ei;
    const int* dstE = ei + E;

    auto alignup = [](size_t v) { return (v + 255) & ~(size_t)255; };
    char* p = (char*)d_ws;
    int* counts  = (int*)p; p += alignup((size_t)n * 4);
    int* row_ptr = (int*)p; p += alignup((size_t)(n + 1) * 4);
    int nb = (n + 1023) / 1024;
    int* bsums   = (int*)p; p += alignup((size_t)nb * 4);
    int* cursor  = (int*)p; p += alignup((size_t)n * 4);
    int* csr     = (int*)p; p += alignup((size_t)(E + n) * 4);
    unsigned int* H2 = (unsigned int*)p; p += alignup((size_t)n * 32 * 4);  // bf16 [n][64]
    float* S     = (float*)p; p += alignup((size_t)n * 4);
    float* Dv    = (float*)p; p += alignup((size_t)n * 4);
    float* stats = (float*)p; p += alignup(128 * 4);
    float* bnsc  = (float*)p; p += alignup(64 * 4);
    float* bnsh  = (float*)p; p += alignup(64 * 4);
    float* T     = (float*)d_out;  // layer ping buffer; final aggregate rewrites it
    unsigned short* H16 = (unsigned short*)H2;

    // ---- CSR build (edges identical across all 5 layers) ----
    k_init_counts<<<(n + 255) / 256, 256, 0, stream>>>(counts, n);
    k_hist<<<1024, 256, 0, stream>>>(dstE, E / 4, counts);
    k_scan_block<<<nb, 256, 0, stream>>>(counts, row_ptr, bsums, n);
    k_scan_bsums<<<1, 64, 0, stream>>>(bsums, nb, row_ptr + n);
    k_scan_add<<<nb, 256, 0, stream>>>(row_ptr, bsums, n);
    k_selfloop<<<(n + 255) / 256, 256, 0, stream>>>(row_ptr, csr, cursor, n);
    k_scatter<<<1024, 256, 0, stream>>>(srcE, dstE, E / 4, cursor, csr);

    int gb = (n + 3) / 4;        // aggregate grid (4 nodes/block)
    int gg = (n + 63) / 64;      // gemm grid (64 nodes/block)

    // ---- input GAT layer ----
    k_gemm<128, 0><<<gg, 256, 0, stream>>>(x, W_in, a_src_in, a_dst_in, nullptr, nullptr,
                                           H16, S, Dv, n);
    k_aggregate<<<gb, 256, 0, stream>>>(H2, S, Dv, row_ptr, csr, b_in, T, n);

    // ---- mid layers: gat -> BN stats; BN+ReLU fused into next gemm's input ----
    for (int l = 0; l < 3; l++) {
        if (l == 0)
            k_gemm<64, 0><<<gg, 256, 0, stream>>>(T, W_mid + l * 4096, a_src_mid + l * 64,
                                                  a_dst_mid + l * 64, nullptr, nullptr,
                                                  H16, S, Dv, n);
        else
            k_gemm<64, 1><<<gg, 256, 0, stream>>>(T, W_mid + l * 4096, a_src_mid + l * 64,
                                                  a_dst_mid + l * 64, bnsc, bnsh,
                                                  H16, S, Dv, n);
        k_aggregate<<<gb, 256, 0, stream>>>(H2, S, Dv, row_ptr, csr, b_mid + l * 64, T, n);
        k_zero_stats<<<1, 128, 0, stream>>>(stats);
        k_colstats<<<512, 256, 0, stream>>>(T, n, stats, stats + 64);
        k_bn_finalize<<<1, 64, 0, stream>>>(stats, stats + 64, gamma + l * 64, beta + l * 64,
                                            n, bnsc, bnsh);
    }

    // ---- output GAT layer (consumes BN+ReLU of last mid layer) ----
    k_gemm<64, 1><<<gg, 256, 0, stream>>>(T, W_out, a_src_out, a_dst_out, bnsc, bnsh,
                                          H16, S, Dv, n);
    k_aggregate<<<gb, 256, 0, stream>>>(H2, S, Dv, row_ptr, csr, b_out, (float*)d_out, n);
}

// Round 5
// 493.529 us; speedup vs baseline: 1.8260x; 1.1456x over previous
//
#include <hip/hip_runtime.h>
#include <math.h>

#define NEG_SLOPE 0.2f
#define BN_EPS 1e-5f
#define BSHIFT 10
#define BSIZE 1024
#define BIN_CHUNK 8192

static __device__ __forceinline__ float wave_red_sum(float v) {
    for (int off = 32; off; off >>= 1) v += __shfl_xor(v, off);
    return v;
}

// fp32 -> bf16 bits, round-to-nearest-even
static __device__ __forceinline__ unsigned short f2bf(float f) {
    unsigned int u = __float_as_uint(f);
    unsigned int r = u + 0x7FFFu + ((u >> 16) & 1u);
    return (unsigned short)(r >> 16);
}

// ---------------- binned CSR build ----------------
// Buckets = 1024-node dst ranges (NB = ceil(n/1024) <= 64 assumed; n=50000 -> 49).

__global__ void k_zero64(int* p, int m) {
    if (threadIdx.x < m) p[threadIdx.x] = 0;
}

__global__ void __launch_bounds__(256) k_bucket_count(const int* __restrict__ dst, int E4,
                                                      int* __restrict__ bcnt) {
    __shared__ int lc[64];
    if (threadIdx.x < 64) lc[threadIdx.x] = 0;
    __syncthreads();
    const int4* d4 = (const int4*)dst;
    int stride = gridDim.x * blockDim.x;
    for (int i = blockIdx.x * blockDim.x + threadIdx.x; i < E4; i += stride) {
        int4 v = d4[i];
        atomicAdd(&lc[v.x >> BSHIFT], 1);
        atomicAdd(&lc[v.y >> BSHIFT], 1);
        atomicAdd(&lc[v.z >> BSHIFT], 1);
        atomicAdd(&lc[v.w >> BSHIFT], 1);
    }
    __syncthreads();
    if (threadIdx.x < 64 && lc[threadIdx.x] > 0)
        atomicAdd(&bcnt[threadIdx.x], lc[threadIdx.x]);
}

// single-wave exclusive scan of bucket counts -> bstart[0..NB], gcursor init
__global__ void k_bucket_scan(const int* __restrict__ bcnt, int NB,
                              int* __restrict__ bstart, int* __restrict__ gcursor) {
    int lane = threadIdx.x;
    int c = (lane < NB) ? bcnt[lane] : 0;
    int v = c;
    for (int off = 1; off < 64; off <<= 1) {
        int t = __shfl_up(v, off);
        if (lane >= off) v += t;
    }
    int excl = v - c;
    if (lane < NB) { bstart[lane] = excl; gcursor[lane] = excl; }
    if (lane == NB - 1) bstart[NB] = v;
}

// bin edges into per-bucket streams; block reserves contiguous space per bucket
__global__ void __launch_bounds__(256) k_bin(const int* __restrict__ src,
                                             const int* __restrict__ dst, int E,
                                             int* __restrict__ gcursor,
                                             int2* __restrict__ binned) {
    __shared__ int lc[64], lbase[64];
    int e0 = blockIdx.x * BIN_CHUNK;
    int e1 = min(e0 + BIN_CHUNK, E);
    if (threadIdx.x < 64) lc[threadIdx.x] = 0;
    __syncthreads();
    for (int i = e0 + threadIdx.x; i < e1; i += 256)
        atomicAdd(&lc[dst[i] >> BSHIFT], 1);
    __syncthreads();
    if (threadIdx.x < 64) {
        int c = lc[threadIdx.x];
        if (c > 0) lbase[threadIdx.x] = atomicAdd(&gcursor[threadIdx.x], c);
    }
    __syncthreads();
    if (threadIdx.x < 64) lc[threadIdx.x] = 0;
    __syncthreads();
    for (int i = e0 + threadIdx.x; i < e1; i += 256) {
        int d = dst[i];
        int b = d >> BSHIFT;
        int pos = lbase[b] + atomicAdd(&lc[b], 1);
        binned[pos] = make_int2(src[i], d);
    }
}

// one block per bucket: per-node counts, LDS scan, self-loop, LDS-cursor scatter
__global__ void __launch_bounds__(256) k_bucket_csr(
    const int2* __restrict__ binned, const int* __restrict__ bstart, int n, int NB,
    int* __restrict__ row_ptr, int* __restrict__ csr_src) {
    __shared__ int cnt[BSIZE];
    __shared__ int wsum[256];
    int b = blockIdx.x;
    int node0 = b << BSHIFT;
    int nnodes = min(BSIZE, n - node0);
    int tid = threadIdx.x;
    #pragma unroll
    for (int i = tid; i < BSIZE; i += 256) cnt[i] = (i < nnodes) ? 1 : 0;  // self loop
    __syncthreads();
    int ebeg = bstart[b], eend = bstart[b + 1];
    for (int i = ebeg + tid; i < eend; i += 256)
        atomicAdd(&cnt[binned[i].y & (BSIZE - 1)], 1);
    __syncthreads();
    int base4 = tid * 4;
    int v0 = cnt[base4], v1 = cnt[base4 + 1], v2 = cnt[base4 + 2], v3 = cnt[base4 + 3];
    int s = v0 + v1 + v2 + v3;
    wsum[tid] = s;
    __syncthreads();
    for (int off = 1; off < 256; off <<= 1) {
        int t = (tid >= off) ? wsum[tid - off] : 0;
        __syncthreads();
        wsum[tid] += t;
        __syncthreads();
    }
    int excl = wsum[tid] - s;
    int csr_base = ebeg + node0;  // edges before bucket + self-loops before bucket
    int e = excl;
    int vv[4] = {v0, v1, v2, v3};
    #pragma unroll
    for (int j = 0; j < 4; j++) {
        int nl = base4 + j;
        int node = node0 + nl;
        if (nl < nnodes) {
            row_ptr[node] = csr_base + e;
            csr_src[csr_base + e] = node;  // self loop first
        }
        cnt[nl] = e + 1;  // local cursor after self loop
        e += vv[j];
    }
    if (b == NB - 1 && tid == 255) row_ptr[n] = csr_base + wsum[255];
    __syncthreads();
    for (int i = ebeg + tid; i < eend; i += 256) {
        int2 e2 = binned[i];
        int pos = csr_base + atomicAdd(&cnt[e2.y & (BSIZE - 1)], 1);
        csr_src[pos] = e2.x;
    }
}

// ---------------- tiled per-layer GEMM: H(bf16) = act(X) @ W, fused scores ----------------
template <int FIN, int USE_BN>
__global__ void __launch_bounds__(256) k_gemm(
    const float* __restrict__ X, const float* __restrict__ W,
    const float* __restrict__ a_src, const float* __restrict__ a_dst,
    const float* __restrict__ bn_sc, const float* __restrict__ bn_sh,
    unsigned short* __restrict__ H16, float* __restrict__ S, float* __restrict__ Dv, int n) {
    __shared__ float Xl[64 * FIN];
    __shared__ float Wl[FIN * 64];
    const int node0 = blockIdx.x * 64;
    const int ROWF4 = FIN / 4;

    {
        const float4* W4 = (const float4*)W;
        float4* Wl4 = (float4*)Wl;
        for (int f = threadIdx.x; f < FIN * 16; f += 256) Wl4[f] = W4[f];
    }
    {
        const float4* X4 = (const float4*)X;
        float4* Xl4 = (float4*)Xl;
        for (int f = threadIdx.x; f < 64 * ROWF4; f += 256) {
            int r = f / ROWF4, c = f % ROWF4;
            float4 v = make_float4(0.f, 0.f, 0.f, 0.f);
            if (node0 + r < n) v = X4[(size_t)(node0 + r) * ROWF4 + c];
            if (USE_BN) {
                int k = c * 4;
                v.x = fmaxf(fmaf(v.x, bn_sc[k + 0], bn_sh[k + 0]), 0.f);
                v.y = fmaxf(fmaf(v.y, bn_sc[k + 1], bn_sh[k + 1]), 0.f);
                v.z = fmaxf(fmaf(v.z, bn_sc[k + 2], bn_sh[k + 2]), 0.f);
                v.w = fmaxf(fmaf(v.w, bn_sc[k + 3], bn_sh[k + 3]), 0.f);
            }
            Xl4[f] = v;
        }
    }
    __syncthreads();

    const int wave = threadIdx.x >> 6, lane = threadIdx.x & 63;
    const int nbase = wave * 16;
    float acc[16];
    #pragma unroll
    for (int i = 0; i < 16; i++) acc[i] = 0.f;

    const float4* Xl4 = (const float4*)Xl;
    for (int kg = 0; kg < ROWF4; kg++) {
        float w0 = Wl[(kg * 4 + 0) * 64 + lane];
        float w1 = Wl[(kg * 4 + 1) * 64 + lane];
        float w2 = Wl[(kg * 4 + 2) * 64 + lane];
        float w3 = Wl[(kg * 4 + 3) * 64 + lane];
        #pragma unroll
        for (int i = 0; i < 16; i++) {
            float4 xv = Xl4[(nbase + i) * ROWF4 + kg];
            acc[i] = fmaf(xv.x, w0, acc[i]);
            acc[i] = fmaf(xv.y, w1, acc[i]);
            acc[i] = fmaf(xv.z, w2, acc[i]);
            acc[i] = fmaf(xv.w, w3, acc[i]);
        }
    }

    float asl = a_src[lane], adl = a_dst[lane];
    #pragma unroll
    for (int i = 0; i < 16; i++) {
        int node = node0 + nbase + i;
        if (node < n) {
            H16[(size_t)node * 64 + lane] = f2bf(acc[i]);
            float ps = wave_red_sum(acc[i] * asl);
            float pd = wave_red_sum(acc[i] * adl);
            if (lane == 0) { S[node] = ps; Dv[node] = pd; }
        }
    }
}

// ---------------- node-parallel GAT aggregate (bf16 H gather) ----------------
__global__ void __launch_bounds__(256) k_aggregate(
    const unsigned int* __restrict__ H2, const float* __restrict__ S,
    const float* __restrict__ Dv,
    const int* __restrict__ row_ptr, const int* __restrict__ csr_src,
    const float* __restrict__ bias, float* __restrict__ out, int n) {
    int wave = threadIdx.x >> 6, lane = threadIdx.x & 63;
    int node = blockIdx.x * 4 + wave;
    if (node >= n) return;
    int start = row_ptr[node], end = row_ptr[node + 1];
    float dn = Dv[node];
    int half = lane >> 5;
    int col = lane & 31;
    float accL0 = 0.f, accH0 = 0.f, accL1 = 0.f, accH1 = 0.f;
    float zlane = 0.f;
    for (int base = start; base < end; base += 64) {
        int cnt = min(64, end - base);
        int sj = 0;
        float w = 0.f;
        if (lane < cnt) {
            sj = csr_src[base + lane];
            float t = S[sj] + dn;
            t = (t > 0.f) ? t : NEG_SLOPE * t;
            w = __expf(t);
        }
        zlane += w;
        for (int jj = 0; jj < cnt; jj += 4) {
            int i0 = min(jj + half, 63);
            int i1 = min(jj + 2 + half, 63);
            float w0 = __shfl(w, i0);
            float w1 = __shfl(w, i1);
            int s0 = __shfl(sj, i0);
            int s1 = __shfl(sj, i1);
            unsigned int u0 = H2[(size_t)s0 * 32 + col];
            unsigned int u1 = H2[(size_t)s1 * 32 + col];
            float l0 = __uint_as_float(u0 << 16);
            float h0 = __uint_as_float(u0 & 0xFFFF0000u);
            float l1 = __uint_as_float(u1 << 16);
            float h1 = __uint_as_float(u1 & 0xFFFF0000u);
            accL0 = fmaf(w0, l0, accL0);
            accH0 = fmaf(w0, h0, accH0);
            accL1 = fmaf(w1, l1, accL1);
            accH1 = fmaf(w1, h1, accH1);
        }
    }
    float z = wave_red_sum(zlane);
    float accL = accL0 + accL1;
    float accH = accH0 + accH1;
    accL += __shfl_xor(accL, 32);
    accH += __shfl_xor(accH, 32);
    if (half == 0) {
        float2 b2 = ((const float2*)bias)[col];
        float2 o;
        o.x = accL / z + b2.x;
        o.y = accH / z + b2.y;
        ((float2*)out)[(size_t)node * 32 + col] = o;
    }
}

// ---------------- batchnorm stats ----------------
__global__ void k_zero_stats(float* stats) {
    if (threadIdx.x < 128) stats[threadIdx.x] = 0.f;
}

__global__ void __launch_bounds__(256) k_colstats(const float* __restrict__ T, int n,
                                                  float* __restrict__ sums,
                                                  float* __restrict__ sumsq) {
    __shared__ float ls[256], lq[256];
    int f = threadIdx.x & 63;
    int rowgrp = threadIdx.x >> 6;
    float s = 0.f, q = 0.f;
    for (int r = blockIdx.x * 4 + rowgrp; r < n; r += gridDim.x * 4) {
        float v = T[(size_t)r * 64 + f];
        s += v;
        q += v * v;
    }
    ls[threadIdx.x] = s; lq[threadIdx.x] = q;
    __syncthreads();
    if (threadIdx.x < 128) {
        ls[threadIdx.x] += ls[threadIdx.x + 128];
        lq[threadIdx.x] += lq[threadIdx.x + 128];
    }
    __syncthreads();
    if (threadIdx.x < 64) {
        atomicAdd(&sums[f], ls[threadIdx.x] + ls[threadIdx.x + 64]);
        atomicAdd(&sumsq[f], lq[threadIdx.x] + lq[threadIdx.x + 64]);
    }
}

__global__ void k_bn_finalize(const float* __restrict__ sums, const float* __restrict__ sumsq,
                              const float* __restrict__ g, const float* __restrict__ be,
                              int n, float* __restrict__ sc, float* __restrict__ sh) {
    int f = threadIdx.x;
    if (f < 64) {
        float inv_n = 1.f / (float)n;
        float mu = sums[f] * inv_n;
        float var = sumsq[f] * inv_n - mu * mu;
        float rstd = rsqrtf(var + BN_EPS);
        float scale = rstd * g[f];
        sc[f] = scale;
        sh[f] = be[f] - mu * scale;
    }
}

extern "C" void kernel_launch(void* const* d_in, const int* in_sizes, int n_in,
                              void* d_out, int out_size, void* d_ws, size_t ws_size,
                              hipStream_t stream) {
    const float* x        = (const float*)d_in[0];
    const int*   ei       = (const int*)d_in[1];
    const float* W_in     = (const float*)d_in[2];
    const float* a_src_in = (const float*)d_in[3];
    const float* a_dst_in = (const float*)d_in[4];
    const float* b_in     = (const float*)d_in[5];
    const float* W_mid    = (const float*)d_in[6];
    const float* a_src_mid= (const float*)d_in[7];
    const float* a_dst_mid= (const float*)d_in[8];
    const float* b_mid    = (const float*)d_in[9];
    const float* gamma    = (const float*)d_in[10];
    const float* beta     = (const float*)d_in[11];
    const float* W_out    = (const float*)d_in[12];
    const float* a_src_out= (const float*)d_in[13];
    const float* a_dst_out= (const float*)d_in[14];
    const float* b_out    = (const float*)d_in[15];

    int n = in_sizes[0] / 128;   // 50000
    int E = in_sizes[1] / 2;     // 1250000
    const int* srcE = ei;
    const int* dstE = ei + E;
    int NB = (n + BSIZE - 1) >> BSHIFT;   // 49 (<= 64 assumed)

    auto alignup = [](size_t v) { return (v + 255) & ~(size_t)255; };
    char* p = (char*)d_ws;
    int* bcnt    = (int*)p; p += alignup(64 * 4);
    int* bstart  = (int*)p; p += alignup(65 * 4);
    int* gcursor = (int*)p; p += alignup(64 * 4);
    int* row_ptr = (int*)p; p += alignup((size_t)(n + 1) * 4);
    int2* binned = (int2*)p; p += alignup((size_t)E * 8);
    int* csr     = (int*)p; p += alignup((size_t)(E + n) * 4);
    unsigned int* H2 = (unsigned int*)p; p += alignup((size_t)n * 32 * 4);  // bf16 [n][64]
    float* S     = (float*)p; p += alignup((size_t)n * 4);
    float* Dv    = (float*)p; p += alignup((size_t)n * 4);
    float* stats = (float*)p; p += alignup(128 * 4);
    float* bnsc  = (float*)p; p += alignup(64 * 4);
    float* bnsh  = (float*)p; p += alignup(64 * 4);
    float* T     = (float*)d_out;  // layer ping buffer; final aggregate rewrites it
    unsigned short* H16 = (unsigned short*)H2;

    // ---- binned CSR build (edges identical across all 5 layers) ----
    k_zero64<<<1, 64, 0, stream>>>(bcnt, 64);
    k_bucket_count<<<256, 256, 0, stream>>>(dstE, E / 4, bcnt);
    k_bucket_scan<<<1, 64, 0, stream>>>(bcnt, NB, bstart, gcursor);
    k_bin<<<(E + BIN_CHUNK - 1) / BIN_CHUNK, 256, 0, stream>>>(srcE, dstE, E, gcursor, binned);
    k_bucket_csr<<<NB, 256, 0, stream>>>(binned, bstart, n, NB, row_ptr, csr);

    int gb = (n + 3) / 4;        // aggregate grid (4 nodes/block)
    int gg = (n + 63) / 64;      // gemm grid (64 nodes/block)

    // ---- input GAT layer ----
    k_gemm<128, 0><<<gg, 256, 0, stream>>>(x, W_in, a_src_in, a_dst_in, nullptr, nullptr,
                                           H16, S, Dv, n);
    k_aggregate<<<gb, 256, 0, stream>>>(H2, S, Dv, row_ptr, csr, b_in, T, n);

    // ---- mid layers: gat -> BN stats; BN+ReLU fused into next gemm's input ----
    for (int l = 0; l < 3; l++) {
        if (l == 0)
            k_gemm<64, 0><<<gg, 256, 0, stream>>>(T, W_mid + l * 4096, a_src_mid + l * 64,
                                                  a_dst_mid + l * 64, nullptr, nullptr,
                                                  H16, S, Dv, n);
        else
            k_gemm<64, 1><<<gg, 256, 0, stream>>>(T, W_mid + l * 4096, a_src_mid + l * 64,
                                                  a_dst_mid + l * 64, bnsc, bnsh,
                                                  H16, S, Dv, n);
        k_aggregate<<<gb, 256, 0, stream>>>(H2, S, Dv, row_ptr, csr, b_mid + l * 64, T, n);
        k_zero_stats<<<1, 128, 0, stream>>>(stats);
        k_colstats<<<512, 256, 0, stream>>>(T, n, stats, stats + 64);
        k_bn_finalize<<<1, 64, 0, stream>>>(stats, stats + 64, gamma + l * 64, beta + l * 64,
                                            n, bnsc, bnsh);
    }

    // ---- output GAT layer (consumes BN+ReLU of last mid layer) ----
    k_gemm<64, 1><<<gg, 256, 0, stream>>>(T, W_out, a_src_out, a_dst_out, bnsc, bnsh,
                                          H16, S, Dv, n);
    k_aggregate<<<gb, 256, 0, stream>>>(H2, S, Dv, row_ptr, csr, b_out, (float*)d_out, n);
}

// Round 6
// 455.721 us; speedup vs baseline: 1.9775x; 1.0830x over previous
//
#include <hip/hip_runtime.h>
#include <math.h>

#define NEG_SLOPE 0.2f
#define BN_EPS 1e-5f
#define BSHIFT 7
#define BSIZE 128          // nodes per bucket
#define NBMAX 512          // max buckets supported (n <= 65536)
#define BIN_CHUNK 8192

static __device__ __forceinline__ float wave_red_sum(float v) {
    for (int off = 32; off; off >>= 1) v += __shfl_xor(v, off);
    return v;
}

// fp32 -> bf16 bits, round-to-nearest-even
static __device__ __forceinline__ unsigned short f2bf(float f) {
    unsigned int u = __float_as_uint(f);
    unsigned int r = u + 0x7FFFu + ((u >> 16) & 1u);
    return (unsigned short)(r >> 16);
}

// ---------------- binned CSR build ----------------
// Buckets = 128-node dst ranges; n=50000 -> NB=391 blocks for k_bucket_csr.

__global__ void k_zero(int* p, int m) {
    int i = blockIdx.x * blockDim.x + threadIdx.x;
    if (i < m) p[i] = 0;
}

__global__ void __launch_bounds__(256) k_bucket_count(const int* __restrict__ dst, int E4,
                                                      int* __restrict__ bcnt) {
    __shared__ int lc[NBMAX];
    for (int i = threadIdx.x; i < NBMAX; i += 256) lc[i] = 0;
    __syncthreads();
    const int4* d4 = (const int4*)dst;
    int stride = gridDim.x * blockDim.x;
    for (int i = blockIdx.x * blockDim.x + threadIdx.x; i < E4; i += stride) {
        int4 v = d4[i];
        atomicAdd(&lc[v.x >> BSHIFT], 1);
        atomicAdd(&lc[v.y >> BSHIFT], 1);
        atomicAdd(&lc[v.z >> BSHIFT], 1);
        atomicAdd(&lc[v.w >> BSHIFT], 1);
    }
    __syncthreads();
    for (int i = threadIdx.x; i < NBMAX; i += 256)
        if (lc[i] > 0) atomicAdd(&bcnt[i], lc[i]);
}

// block scan (256 thr x 2) of bucket counts -> bstart[0..NB], gcursor init
// bcnt must be zeroed to NBMAX entries.
__global__ void __launch_bounds__(256) k_bucket_scan(const int* __restrict__ bcnt, int NB,
                                                     int* __restrict__ bstart,
                                                     int* __restrict__ gcursor) {
    __shared__ int wsum[256];
    int tid = threadIdx.x;
    int i0 = tid * 2, i1 = tid * 2 + 1;
    int v0 = bcnt[i0], v1 = bcnt[i1];
    int s = v0 + v1;
    wsum[tid] = s;
    __syncthreads();
    for (int off = 1; off < 256; off <<= 1) {
        int t = (tid >= off) ? wsum[tid - off] : 0;
        __syncthreads();
        wsum[tid] += t;
        __syncthreads();
    }
    int excl = wsum[tid] - s;
    if (i0 < NB) { bstart[i0] = excl; gcursor[i0] = excl; }
    excl += v0;
    if (i1 < NB) { bstart[i1] = excl; gcursor[i1] = excl; }
    if (tid == 255) bstart[NB] = wsum[255];
}

// bin edges into per-bucket streams; block reserves contiguous space per bucket
__global__ void __launch_bounds__(256) k_bin(const int* __restrict__ src,
                                             const int* __restrict__ dst, int E,
                                             int* __restrict__ gcursor,
                                             int2* __restrict__ binned) {
    __shared__ int lc[NBMAX], lbase[NBMAX];
    int e0 = blockIdx.x * BIN_CHUNK;
    int e1 = min(e0 + BIN_CHUNK, E);
    for (int i = threadIdx.x; i < NBMAX; i += 256) lc[i] = 0;
    __syncthreads();
    for (int i = e0 + threadIdx.x; i < e1; i += 256)
        atomicAdd(&lc[dst[i] >> BSHIFT], 1);
    __syncthreads();
    for (int i = threadIdx.x; i < NBMAX; i += 256) {
        int c = lc[i];
        if (c > 0) lbase[i] = atomicAdd(&gcursor[i], c);
    }
    __syncthreads();
    for (int i = threadIdx.x; i < NBMAX; i += 256) lc[i] = 0;
    __syncthreads();
    for (int i = e0 + threadIdx.x; i < e1; i += 256) {
        int d = dst[i];
        int b = d >> BSHIFT;
        int pos = lbase[b] + atomicAdd(&lc[b], 1);
        binned[pos] = make_int2(src[i], d);
    }
}

// one block per 128-node bucket: per-node counts, LDS scan, self-loop, scatter
__global__ void __launch_bounds__(256) k_bucket_csr(
    const int2* __restrict__ binned, const int* __restrict__ bstart, int n, int NB,
    int* __restrict__ row_ptr, int* __restrict__ csr_src) {
    __shared__ int cnt[BSIZE];
    __shared__ int wsum[BSIZE];
    int b = blockIdx.x;
    int node0 = b << BSHIFT;
    int nnodes = min(BSIZE, n - node0);
    int tid = threadIdx.x;
    if (tid < BSIZE) cnt[tid] = (tid < nnodes) ? 1 : 0;  // self loop
    __syncthreads();
    int ebeg = bstart[b], eend = bstart[b + 1];
    for (int i = ebeg + tid; i < eend; i += 256)
        atomicAdd(&cnt[binned[i].y & (BSIZE - 1)], 1);
    __syncthreads();
    int c = 0;
    if (tid < BSIZE) { c = cnt[tid]; wsum[tid] = c; }
    __syncthreads();
    for (int off = 1; off < BSIZE; off <<= 1) {
        int t = (tid >= off && tid < BSIZE) ? wsum[tid - off] : 0;
        __syncthreads();
        if (tid < BSIZE) wsum[tid] += t;
        __syncthreads();
    }
    int csr_base = ebeg + node0;  // edges before bucket + self-loops before bucket
    if (tid < BSIZE) {
        int excl = wsum[tid] - c;
        int node = node0 + tid;
        if (tid < nnodes) {
            row_ptr[node] = csr_base + excl;
            csr_src[csr_base + excl] = node;  // self loop first
        }
        cnt[tid] = excl + 1;  // local cursor after self loop
    }
    if (b == NB - 1 && tid == BSIZE - 1) row_ptr[n] = csr_base + wsum[BSIZE - 1];
    __syncthreads();
    for (int i = ebeg + tid; i < eend; i += 256) {
        int2 e2 = binned[i];
        int pos = csr_base + atomicAdd(&cnt[e2.y & (BSIZE - 1)], 1);
        csr_src[pos] = e2.x;
    }
}

// ---------------- tiled per-layer GEMM: H(bf16) = act(X) @ W, fused scores ----------------
template <int FIN, int USE_BN>
__global__ void __launch_bounds__(256) k_gemm(
    const float* __restrict__ X, const float* __restrict__ W,
    const float* __restrict__ a_src, const float* __restrict__ a_dst,
    const float* __restrict__ bn_sc, const float* __restrict__ bn_sh,
    unsigned short* __restrict__ H16, float* __restrict__ S, float* __restrict__ Dv, int n) {
    __shared__ float Xl[64 * FIN];
    __shared__ float Wl[FIN * 64];
    const int node0 = blockIdx.x * 64;
    const int ROWF4 = FIN / 4;

    {
        const float4* W4 = (const float4*)W;
        float4* Wl4 = (float4*)Wl;
        for (int f = threadIdx.x; f < FIN * 16; f += 256) Wl4[f] = W4[f];
    }
    {
        const float4* X4 = (const float4*)X;
        float4* Xl4 = (float4*)Xl;
        for (int f = threadIdx.x; f < 64 * ROWF4; f += 256) {
            int r = f / ROWF4, c = f % ROWF4;
            float4 v = make_float4(0.f, 0.f, 0.f, 0.f);
            if (node0 + r < n) v = X4[(size_t)(node0 + r) * ROWF4 + c];
            if (USE_BN) {
                int k = c * 4;
                v.x = fmaxf(fmaf(v.x, bn_sc[k + 0], bn_sh[k + 0]), 0.f);
                v.y = fmaxf(fmaf(v.y, bn_sc[k + 1], bn_sh[k + 1]), 0.f);
                v.z = fmaxf(fmaf(v.z, bn_sc[k + 2], bn_sh[k + 2]), 0.f);
                v.w = fmaxf(fmaf(v.w, bn_sc[k + 3], bn_sh[k + 3]), 0.f);
            }
            Xl4[f] = v;
        }
    }
    __syncthreads();

    const int wave = threadIdx.x >> 6, lane = threadIdx.x & 63;
    const int nbase = wave * 16;
    float acc[16];
    #pragma unroll
    for (int i = 0; i < 16; i++) acc[i] = 0.f;

    const float4* Xl4 = (const float4*)Xl;
    for (int kg = 0; kg < ROWF4; kg++) {
        float w0 = Wl[(kg * 4 + 0) * 64 + lane];
        float w1 = Wl[(kg * 4 + 1) * 64 + lane];
        float w2 = Wl[(kg * 4 + 2) * 64 + lane];
        float w3 = Wl[(kg * 4 + 3) * 64 + lane];
        #pragma unroll
        for (int i = 0; i < 16; i++) {
            float4 xv = Xl4[(nbase + i) * ROWF4 + kg];
            acc[i] = fmaf(xv.x, w0, acc[i]);
            acc[i] = fmaf(xv.y, w1, acc[i]);
            acc[i] = fmaf(xv.z, w2, acc[i]);
            acc[i] = fmaf(xv.w, w3, acc[i]);
        }
    }

    float asl = a_src[lane], adl = a_dst[lane];
    #pragma unroll
    for (int i = 0; i < 16; i++) {
        int node = node0 + nbase + i;
        if (node < n) {
            H16[(size_t)node * 64 + lane] = f2bf(acc[i]);
            float ps = wave_red_sum(acc[i] * asl);
            float pd = wave_red_sum(acc[i] * adl);
            if (lane == 0) { S[node] = ps; Dv[node] = pd; }
        }
    }
}

// ---------------- node-parallel GAT aggregate (bf16 H gather) ----------------
__global__ void __launch_bounds__(256) k_aggregate(
    const unsigned int* __restrict__ H2, const float* __restrict__ S,
    const float* __restrict__ Dv,
    const int* __restrict__ row_ptr, const int* __restrict__ csr_src,
    const float* __restrict__ bias, float* __restrict__ out, int n) {
    int wave = threadIdx.x >> 6, lane = threadIdx.x & 63;
    int node = blockIdx.x * 4 + wave;
    if (node >= n) return;
    int start = row_ptr[node], end = row_ptr[node + 1];
    float dn = Dv[node];
    int half = lane >> 5;
    int col = lane & 31;
    float accL0 = 0.f, accH0 = 0.f, accL1 = 0.f, accH1 = 0.f;
    float zlane = 0.f;
    for (int base = start; base < end; base += 64) {
        int cnt = min(64, end - base);
        int sj = 0;
        float w = 0.f;
        if (lane < cnt) {
            sj = csr_src[base + lane];
            float t = S[sj] + dn;
            t = (t > 0.f) ? t : NEG_SLOPE * t;
            w = __expf(t);
        }
        zlane += w;
        for (int jj = 0; jj < cnt; jj += 4) {
            int i0 = min(jj + half, 63);
            int i1 = min(jj + 2 + half, 63);
            float w0 = __shfl(w, i0);
            float w1 = __shfl(w, i1);
            int s0 = __shfl(sj, i0);
            int s1 = __shfl(sj, i1);
            unsigned int u0 = H2[(size_t)s0 * 32 + col];
            unsigned int u1 = H2[(size_t)s1 * 32 + col];
            float l0 = __uint_as_float(u0 << 16);
            float h0 = __uint_as_float(u0 & 0xFFFF0000u);
            float l1 = __uint_as_float(u1 << 16);
            float h1 = __uint_as_float(u1 & 0xFFFF0000u);
            accL0 = fmaf(w0, l0, accL0);
            accH0 = fmaf(w0, h0, accH0);
            accL1 = fmaf(w1, l1, accL1);
            accH1 = fmaf(w1, h1, accH1);
        }
    }
    float z = wave_red_sum(zlane);
    float accL = accL0 + accL1;
    float accH = accH0 + accH1;
    accL += __shfl_xor(accL, 32);
    accH += __shfl_xor(accH, 32);
    if (half == 0) {
        float2 b2 = ((const float2*)bias)[col];
        float2 o;
        o.x = accL / z + b2.x;
        o.y = accH / z + b2.y;
        ((float2*)out)[(size_t)node * 32 + col] = o;
    }
}

// ---------------- batchnorm stats ----------------
__global__ void k_zero_stats(float* stats) {
    if (threadIdx.x < 128) stats[threadIdx.x] = 0.f;
}

__global__ void __launch_bounds__(256) k_colstats(const float* __restrict__ T, int n,
                                                  float* __restrict__ sums,
                                                  float* __restrict__ sumsq) {
    __shared__ float ls[256], lq[256];
    int f = threadIdx.x & 63;
    int rowgrp = threadIdx.x >> 6;
    float s = 0.f, q = 0.f;
    for (int r = blockIdx.x * 4 + rowgrp; r < n; r += gridDim.x * 4) {
        float v = T[(size_t)r * 64 + f];
        s += v;
        q += v * v;
    }
    ls[threadIdx.x] = s; lq[threadIdx.x] = q;
    __syncthreads();
    if (threadIdx.x < 128) {
        ls[threadIdx.x] += ls[threadIdx.x + 128];
        lq[threadIdx.x] += lq[threadIdx.x + 128];
    }
    __syncthreads();
    if (threadIdx.x < 64) {
        atomicAdd(&sums[f], ls[threadIdx.x] + ls[threadIdx.x + 64]);
        atomicAdd(&sumsq[f], lq[threadIdx.x] + lq[threadIdx.x + 64]);
    }
}

__global__ void k_bn_finalize(const float* __restrict__ sums, const float* __restrict__ sumsq,
                              const float* __restrict__ g, const float* __restrict__ be,
                              int n, float* __restrict__ sc, float* __restrict__ sh) {
    int f = threadIdx.x;
    if (f < 64) {
        float inv_n = 1.f / (float)n;
        float mu = sums[f] * inv_n;
        float var = sumsq[f] * inv_n - mu * mu;
        float rstd = rsqrtf(var + BN_EPS);
        float scale = rstd * g[f];
        sc[f] = scale;
        sh[f] = be[f] - mu * scale;
    }
}

extern "C" void kernel_launch(void* const* d_in, const int* in_sizes, int n_in,
                              void* d_out, int out_size, void* d_ws, size_t ws_size,
                              hipStream_t stream) {
    const float* x        = (const float*)d_in[0];
    const int*   ei       = (const int*)d_in[1];
    const float* W_in     = (const float*)d_in[2];
    const float* a_src_in = (const float*)d_in[3];
    const float* a_dst_in = (const float*)d_in[4];
    const float* b_in     = (const float*)d_in[5];
    const float* W_mid    = (const float*)d_in[6];
    const float* a_src_mid= (const float*)d_in[7];
    const float* a_dst_mid= (const float*)d_in[8];
    const float* b_mid    = (const float*)d_in[9];
    const float* gamma    = (const float*)d_in[10];
    const float* beta     = (const float*)d_in[11];
    const float* W_out    = (const float*)d_in[12];
    const float* a_src_out= (const float*)d_in[13];
    const float* a_dst_out= (const float*)d_in[14];
    const float* b_out    = (const float*)d_in[15];

    int n = in_sizes[0] / 128;   // 50000
    int E = in_sizes[1] / 2;     // 1250000
    const int* srcE = ei;
    const int* dstE = ei + E;
    int NB = (n + BSIZE - 1) >> BSHIFT;   // 391 (<= NBMAX assumed)

    auto alignup = [](size_t v) { return (v + 255) & ~(size_t)255; };
    char* p = (char*)d_ws;
    int* bcnt    = (int*)p; p += alignup(NBMAX * 4);
    int* bstart  = (int*)p; p += alignup((NBMAX + 1) * 4);
    int* gcursor = (int*)p; p += alignup(NBMAX * 4);
    int* row_ptr = (int*)p; p += alignup((size_t)(n + 1) * 4);
    int2* binned = (int2*)p; p += alignup((size_t)E * 8);
    int* csr     = (int*)p; p += alignup((size_t)(E + n) * 4);
    unsigned int* H2 = (unsigned int*)p; p += alignup((size_t)n * 32 * 4);  // bf16 [n][64]
    float* S     = (float*)p; p += alignup((size_t)n * 4);
    float* Dv    = (float*)p; p += alignup((size_t)n * 4);
    float* stats = (float*)p; p += alignup(128 * 4);
    float* bnsc  = (float*)p; p += alignup(64 * 4);
    float* bnsh  = (float*)p; p += alignup(64 * 4);
    float* T     = (float*)d_out;  // layer ping buffer; final aggregate rewrites it
    unsigned short* H16 = (unsigned short*)H2;

    // ---- binned CSR build (edges identical across all 5 layers) ----
    k_zero<<<(NBMAX + 255) / 256, 256, 0, stream>>>(bcnt, NBMAX);
    k_bucket_count<<<256, 256, 0, stream>>>(dstE, E / 4, bcnt);
    k_bucket_scan<<<1, 256, 0, stream>>>(bcnt, NB, bstart, gcursor);
    k_bin<<<(E + BIN_CHUNK - 1) / BIN_CHUNK, 256, 0, stream>>>(srcE, dstE, E, gcursor, binned);
    k_bucket_csr<<<NB, 256, 0, stream>>>(binned, bstart, n, NB, row_ptr, csr);

    int gb = (n + 3) / 4;        // aggregate grid (4 nodes/block)
    int gg = (n + 63) / 64;      // gemm grid (64 nodes/block)

    // ---- input GAT layer ----
    k_gemm<128, 0><<<gg, 256, 0, stream>>>(x, W_in, a_src_in, a_dst_in, nullptr, nullptr,
                                           H16, S, Dv, n);
    k_aggregate<<<gb, 256, 0, stream>>>(H2, S, Dv, row_ptr, csr, b_in, T, n);

    // ---- mid layers: gat -> BN stats; BN+ReLU fused into next gemm's input ----
    for (int l = 0; l < 3; l++) {
        if (l == 0)
            k_gemm<64, 0><<<gg, 256, 0, stream>>>(T, W_mid + l * 4096, a_src_mid + l * 64,
                                                  a_dst_mid + l * 64, nullptr, nullptr,
                                                  H16, S, Dv, n);
        else
            k_gemm<64, 1><<<gg, 256, 0, stream>>>(T, W_mid + l * 4096, a_src_mid + l * 64,
                                                  a_dst_mid + l * 64, bnsc, bnsh,
                                                  H16, S, Dv, n);
        k_aggregate<<<gb, 256, 0, stream>>>(H2, S, Dv, row_ptr, csr, b_mid + l * 64, T, n);
        k_zero_stats<<<1, 128, 0, stream>>>(stats);
        k_colstats<<<512, 256, 0, stream>>>(T, n, stats, stats + 64);
        k_bn_finalize<<<1, 64, 0, stream>>>(stats, stats + 64, gamma + l * 64, beta + l * 64,
                                            n, bnsc, bnsh);
    }

    // ---- output GAT layer (consumes BN+ReLU of last mid layer) ----
    k_gemm<64, 1><<<gg, 256, 0, stream>>>(T, W_out, a_src_out, a_dst_out, bnsc, bnsh,
                                          H16, S, Dv, n);
    k_aggregate<<<gb, 256, 0, stream>>>(H2, S, Dv, row_ptr, csr, b_out, (float*)d_out, n);
}